// Round 5
// baseline (518.817 us; speedup 1.0000x reference)
//
#include <hip/hip_runtime.h>

// Problem constants (B=4, T=S=1024, E=1024, CTX=768, H=16, DH=64)
#define NB 4
#define TT 1024
#define SS 1024
#define EE 1024
#define CCH 768
#define NH 16
#define DHH 64
#define EPSF 1e-5f
// SCALE = 1024 // (16**0.5) = 256.  Fold 1/256 * log2(e) into q so that
// exp(score/256) == exp2(q'.k) with a single v_exp_f32.
#define QSCALE (1.4426950408889634f / 256.0f)

#define GRID_BLKS 512   // 2 blocks/CU guaranteed co-resident (LDS 50176 -> 3/CU cap)

typedef unsigned short u16;
typedef __attribute__((ext_vector_type(8))) short short8;       // MFMA A/B frag
typedef __attribute__((ext_vector_type(8))) unsigned short u16x8;
typedef __attribute__((ext_vector_type(4))) unsigned short u16x4;
typedef __attribute__((ext_vector_type(4))) float f32x4;        // MFMA C/D frag

__device__ __forceinline__ u16 f2bu(float f) {
    union { float f; unsigned u; } x; x.f = f;
    unsigned r = x.u + 0x7fffu + ((x.u >> 16) & 1u);
    return (u16)(r >> 16);
}
__device__ __forceinline__ float bu2f(u16 u) {
    union { unsigned u; float f; } x; x.u = ((unsigned)u) << 16; return x.f;
}

#if __has_builtin(__builtin_amdgcn_exp2f)
#define EXP2(x) __builtin_amdgcn_exp2f(x)
#else
#define EXP2(x) exp2f(x)
#endif

#define MFMA16(a, b, c) __builtin_amdgcn_mfma_f32_16x16x32_bf16((a), (b), (c), 0, 0, 0)

// ---------------------------------------------------------------------------
// Software grid barrier (graph-capture-safe replacement for cooperative
// launch).  Monotonic per-phase ticket counters: correct across graph
// replays / rocprof re-dispatches without any reset.  All 512 blocks are
// guaranteed co-resident (LDS 50176 B -> 3 blocks/CU cap; launch_bounds
// (256,2) -> VGPR<=256 -> >=2 blocks/CU -> capacity 512).
// atomicAdd on global is device-scope on gfx950; __threadfence() is the
// agent-scope acq_rel fence (L2 writeback + invalidate for cross-XCD).
// ---------------------------------------------------------------------------
__device__ unsigned int g_cnt[8];   // zero-initialized at module load

__device__ __forceinline__ void grid_barrier(int idx) {
    __syncthreads();
    if (threadIdx.x == 0) {
        __threadfence();   // release: make this block's stores visible
        unsigned ticket = atomicAdd(&g_cnt[idx], 1u);
        unsigned target = (ticket / GRID_BLKS + 1u) * GRID_BLKS;
        while (atomicAdd(&g_cnt[idx], 0u) < target)
            __builtin_amdgcn_s_sleep(2);
        __threadfence();   // acquire: invalidate stale caches before reads
    }
    __syncthreads();
}

// ---------------------------------------------------------------------------
// Async global->LDS staging (16B/lane).  LDS tiles are LINEAR [R][64] u16
// (128B rows); content XOR-swizzled: logical (row, bytecol) lives at physical
// (row, bytecol ^ ((row&7)<<4)).  Swizzle applied on the GLOBAL source
// address (linear dest + inverse-swizzled source + swizzled read).
// ---------------------------------------------------------------------------
__device__ __forceinline__ void gload16(const void* g, void* l) {
    __builtin_amdgcn_global_load_lds(
        (const __attribute__((address_space(1))) void*)g,
        (__attribute__((address_space(3))) void*)l, 16, 0, 0);
}

template<int R>
__device__ __forceinline__ void stage_tile(
    const u16* __restrict__ g, int ldg, u16* lds, int w, int lane) {
    constexpr int PW = R / 32;               // insts per wave
    int r0 = lane >> 3;                      // row within 8-row group == row&7
    int cs = ((lane & 7) << 4) ^ (r0 << 4);  // swizzled source byte col
#pragma unroll
    for (int j = 0; j < PW; j++) {
        int inst = w * PW + j;
        const u16* src = g + (size_t)(inst * 8 + r0) * ldg + (cs >> 1);
        gload16(src, lds + inst * 512);
    }
}

__device__ __forceinline__ const u16* swz_ptr(const u16* tile, int row, int col) {
    int off = row * 128 + ((col * 2) ^ ((row & 7) << 4));
    return (const u16*)((const char*)tile + off);
}

// prep block-range offsets
#define PREP_WS_END   4096                  // 4 mats x 1024 rows
#define PREP_SCAN_END (PREP_WS_END + 8)     // 2 masks x 4 batches
#define PREP_TR_END   (PREP_SCAN_END + 1792) // 16 x 28 x 4 transpose tiles
#define PREP_FILL_END (PREP_TR_END + 4096)  // 4 batches x 1024 rows fill

// ---------------------------------------------------------------------------
// Shared-memory union across the 5 phases (max 50176 B).
// ---------------------------------------------------------------------------
union SMem {
    struct {
        float tile[64][65];
        int spos[64], smask[64], wtoti[4];
        float sa[4], sb2[4], smean, srstd;
    } pr;
    struct {
        u16 at[2][128][64];
        u16 bt[2][64][64];
        float sg[64], sbe[64], sbias[128];
    } qk;                                   // 50176 B
    struct {
        u16 kt[64][64];
        u16 qt[2][64][64];
        float lp[4][64];
    } st;
    struct {
        u16 at[2][64][64];
        u16 bt[2][64][64];
        u16 pt[64][72];
    } pv;
    struct {
        u16 at[2][128][64];
        u16 bt[2][64][64];
        float sbias[128];
        int stre[64];
    } po;
};

struct KArgs {
    const float *qw, *kw, *vw, *ow;
    u16 *wqn, *wkn, *wvn, *won;
    const float *x, *ctx;
    const int *mask, *mask_ctx;
    u16 *xc, *cc;
    int *tIdx, *sIdx, *cntQ, *cntK;
    float *outF;
    const float *qb, *kb, *vbi, *obi;
    const float *gq, *bq, *gk, *bk, *gv, *bv;
    u16 *qc, *kc, *vn, *ac, *P;
};

// ---------------------------------------------------------------------------
// Phase 1 body: prep (WS-norm / mask scan / compacting transpose / resid fill)
// ---------------------------------------------------------------------------
__device__ void prep_body(int bid, const KArgs& a, SMem& sm) {
    int tid = threadIdx.x;
    if (bid < PREP_WS_END) {
        int mat = bid >> 10, row = bid & 1023;
        const float* w = mat == 0 ? a.qw : (mat == 1 ? a.kw : (mat == 2 ? a.vw : a.ow));
        u16* wn = mat == 0 ? a.wqn : (mat == 1 ? a.wkn : (mat == 2 ? a.wvn : a.won));
        int I = (mat == 1 || mat == 2) ? CCH : EE;
        const float* wr = w + (size_t)row * I;
        int nv = I >> 8;
        float vals[4];
        float s = 0.f, s2 = 0.f;
        for (int j = 0; j < nv; j++) {
            float v = wr[tid + 256 * j];
            vals[j] = v; s += v; s2 += v * v;
        }
#pragma unroll
        for (int off = 32; off > 0; off >>= 1) { s += __shfl_down(s, off); s2 += __shfl_down(s2, off); }
        int wid = tid >> 6;
        if ((tid & 63) == 0) { sm.pr.sa[wid] = s; sm.pr.sb2[wid] = s2; }
        __syncthreads();
        if (tid == 0) {
            float ts = sm.pr.sa[0] + sm.pr.sa[1] + sm.pr.sa[2] + sm.pr.sa[3];
            float ts2 = sm.pr.sb2[0] + sm.pr.sb2[1] + sm.pr.sb2[2] + sm.pr.sb2[3];
            float mean = ts / (float)I;
            float var = ts2 / (float)I - mean * mean;
            sm.pr.smean = mean; sm.pr.srstd = rsqrtf(var + EPSF);
        }
        __syncthreads();
        float mean = sm.pr.smean, r = sm.pr.srstd;
        u16* wo = wn + (size_t)row * I;
        for (int j = 0; j < nv; j++) wo[tid + 256 * j] = f2bu((vals[j] - mean) * r);
        return;
    }
    if (bid < PREP_SCAN_END) {
        int t = bid - PREP_WS_END;
        int which = t & 1, b = t >> 1;
        const int* m = (which ? a.mask_ctx : a.mask) + b * 1024;
        int* idx = (which ? a.sIdx : a.tIdx) + b * 1024;
        int* cnt = (which ? a.cntK : a.cntQ) + b;
        int base = tid * 4;
        int v[4]; int s = 0;
#pragma unroll
        for (int i = 0; i < 4; i++) { v[i] = m[base + i] ? 1 : 0; s += v[i]; }
        int lane = tid & 63, wid = tid >> 6;
        int inc = s;
#pragma unroll
        for (int off = 1; off < 64; off <<= 1) {
            int o = __shfl_up(inc, off);
            if (lane >= off) inc += o;
        }
        if (lane == 63) sm.pr.wtoti[wid] = inc;
        __syncthreads();
        int woff = 0;
        for (int i = 0; i < wid; i++) woff += sm.pr.wtoti[i];
        int p = woff + inc - s;
#pragma unroll
        for (int i = 0; i < 4; i++) {
            if (v[i]) idx[p] = base + i;
            p += v[i];
        }
        if (tid == 255) *cnt = p;
        return;
    }
    if (bid < PREP_TR_END) {
        int t = bid - PREP_SCAN_END;
        int xb = t & 15; int rem = t >> 4;
        int yy = rem % 28, b = rem / 28;
        int mat = yy < 16 ? 0 : 1;
        int r0 = (mat == 0 ? yy : yy - 16) * 64;
        int R = mat == 0 ? EE : CCH;
        const float* in = mat == 0 ? a.x : a.ctx;
        const int* m = (mat == 0 ? a.mask : a.mask_ctx) + (size_t)b * 1024;
        u16* out = mat == 0 ? a.xc : a.cc;
        int c0 = xb * 64;
        const float* ip = in + (size_t)b * R * 1024;
        u16* op = out + (size_t)b * R * 1024;
#pragma unroll
        for (int mm = 0; mm < 16; mm++) {
            int id = tid + 256 * mm; int r = id >> 6, c = id & 63;
            sm.pr.tile[r][c] = ip[(size_t)(r0 + r) * 1024 + c0 + c];
        }
        int base = tid * 4;
        int v[4]; int s = 0;
#pragma unroll
        for (int i = 0; i < 4; i++) { v[i] = m[base + i] ? 1 : 0; s += v[i]; }
        int lane = tid & 63, wid = tid >> 6;
        int inc = s;
#pragma unroll
        for (int off = 1; off < 64; off <<= 1) {
            int o = __shfl_up(inc, off);
            if (lane >= off) inc += o;
        }
        if (lane == 63) sm.pr.wtoti[wid] = inc;
        __syncthreads();
        int woff = 0;
        for (int i = 0; i < wid; i++) woff += sm.pr.wtoti[i];
        int p = woff + inc - s;
#pragma unroll
        for (int i = 0; i < 4; i++) {
            int g = base + i;
            if (g >= c0 && g < c0 + 64) { sm.pr.spos[g - c0] = p; sm.pr.smask[g - c0] = v[i]; }
            p += v[i];
        }
        __syncthreads();
#pragma unroll
        for (int mm = 0; mm < 16; mm++) {
            int id = tid + 256 * mm; int rr = id >> 6, cc2 = id & 63;
            if (sm.pr.smask[rr])
                op[(size_t)sm.pr.spos[rr] * R + r0 + cc2] = f2bu(sm.pr.tile[cc2][rr]);
        }
        return;
    }
    {   // masked residual fill
        int f = bid - PREP_TR_END;
        int b = f >> 10, o = f & 1023;
        const float* xr = a.x + ((size_t)b * EE + o) * TT;
        float* orow = a.outF + ((size_t)b * EE + o) * TT;
        const int* mrow = a.mask + (size_t)b * TT;
        int4 mv = ((const int4*)mrow)[tid];
        float4 xv = ((const float4*)xr)[tid];
        int t4 = tid * 4;
        if (!mv.x) orow[t4 + 0] = xv.x;
        if (!mv.y) orow[t4 + 1] = xv.y;
        if (!mv.z) orow[t4 + 2] = xv.z;
        if (!mv.w) orow[t4 + 3] = xv.w;
    }
}

// ---------------------------------------------------------------------------
// GEMM core: 128x64 tile, 4 waves, each a 64x32 quadrant (4x2 16x16x32 frags).
// global_load_lds staging, double-buffered LDS, one barrier per 64-K-step.
// ---------------------------------------------------------------------------
__device__ __forceinline__ void gemm_core(
    const u16* __restrict__ A, const u16* __restrict__ Bp, int I,
    int o0, int l0, u16 (*at)[128][64], u16 (*bt)[64][64], f32x4 (&acc)[4][2]) {
    int tid = threadIdx.x;
    int w = tid >> 6, lane = tid & 63, quad = lane >> 4, l16 = lane & 15;
    int wm = w & 1, wn = w >> 1;
    const u16* Ab = A + (size_t)o0 * I;
    const u16* Bb = Bp + (size_t)l0 * I;
    stage_tile<128>(Ab, I, &at[0][0][0], w, lane);
    stage_tile<64>(Bb, I, &bt[0][0][0], w, lane);
    __syncthreads();
    int cur = 0;
    for (int k0 = 0; k0 < I; k0 += 64, cur ^= 1) {
        int kn = k0 + 64;
        if (kn < I) {
            stage_tile<128>(Ab + kn, I, &at[cur ^ 1][0][0], w, lane);
            stage_tile<64>(Bb + kn, I, &bt[cur ^ 1][0][0], w, lane);
        }
#pragma unroll
        for (int ks = 0; ks < 64; ks += 32) {
            short8 af[4], bf[2];
#pragma unroll
            for (int i = 0; i < 4; i++)
                af[i] = *(const short8*)swz_ptr(&at[cur][0][0], wm * 64 + i * 16 + l16, ks + quad * 8);
#pragma unroll
            for (int j = 0; j < 2; j++)
                bf[j] = *(const short8*)swz_ptr(&bt[cur][0][0], wn * 32 + j * 16 + l16, ks + quad * 8);
#pragma unroll
            for (int mt = 0; mt < 4; mt++)
#pragma unroll
                for (int nt = 0; nt < 2; nt++)
                    acc[mt][nt] = MFMA16(af[mt], bf[nt], acc[mt][nt]);
        }
        __syncthreads();
    }
}

// ---------------------------------------------------------------------------
// Phase 2 body: fused q/k/v projections + per-head LN epilogue.
// vb decodes the old grid (24, 16, NB).
// ---------------------------------------------------------------------------
__device__ void qkv_body(int vb, const KArgs& a, SMem& sm) {
    int gx = vb % 24, rem = vb / 24;
    int gy = rem & 15, b = rem >> 4;
    int mat = gx >> 3;
    int o0 = (gx & 7) * 128;
    int l0 = gy * 64;
    int limit = (mat == 0) ? a.cntQ[b] : a.cntK[b];
    if (l0 >= limit) return;
    int tid = threadIdx.x;
    int w = tid >> 6, lane = tid & 63, quad = lane >> 4, l16 = lane & 15;
    int wm = w & 1, wn = w >> 1;
    const u16* A = mat == 0 ? a.wqn : (mat == 1 ? a.wkn : a.wvn);
    const u16* BT = mat == 0 ? a.xc : a.cc;
    const float* bias = mat == 0 ? a.qb : (mat == 1 ? a.kb : a.vbi);
    int I = mat == 0 ? EE : CCH;
    if (tid < 64) {
        const float* gsrc = mat == 0 ? a.gq : (mat == 1 ? a.gk : a.gv);
        const float* bsrc = mat == 0 ? a.bq : (mat == 1 ? a.bk : a.bv);
        sm.qk.sg[tid] = gsrc[tid];
        sm.qk.sbe[tid] = bsrc[tid];
    }
    if (tid < 128) sm.qk.sbias[tid] = bias[o0 + tid];

    f32x4 acc[4][2] = {};
    gemm_core(A, BT + (size_t)b * 1024 * I, I, o0, l0, sm.qk.at, sm.qk.bt, acc);

    float scale = mat == 0 ? QSCALE : 1.0f;
    int h = (o0 >> 6) + wm;
    int bh = b * NH + h;
#pragma unroll
    for (int nt = 0; nt < 2; nt++) {
        int l = l0 + wn * 32 + nt * 16 + l16;
        float vbuf[16];
        float s = 0.f;
#pragma unroll
        for (int mt = 0; mt < 4; mt++)
#pragma unroll
            for (int reg = 0; reg < 4; reg++) {
                float v = acc[mt][nt][reg] + sm.qk.sbias[wm * 64 + mt * 16 + quad * 4 + reg];
                vbuf[mt * 4 + reg] = v; s += v;
            }
        s += __shfl_xor(s, 16); s += __shfl_xor(s, 32);
        float mean = s * (1.f / 64);
        float s2 = 0.f;
#pragma unroll
        for (int i = 0; i < 16; i++) { float dv = vbuf[i] - mean; s2 += dv * dv; }
        s2 += __shfl_xor(s2, 16); s2 += __shfl_xor(s2, 32);
        float r = rsqrtf(s2 * (1.f / 64) + EPSF);
        if (l < limit) {
            if (mat < 2) {
                u16* outT = mat == 0 ? a.qc : a.kc;
                u16* op = outT + ((size_t)bh * 1024 + l) * 64;
#pragma unroll
                for (int mt = 0; mt < 4; mt++) {
                    u16x4 pk;
#pragma unroll
                    for (int reg = 0; reg < 4; reg++) {
                        int d = mt * 16 + quad * 4 + reg;
                        pk[reg] = f2bu(((vbuf[mt * 4 + reg] - mean) * r * sm.qk.sg[d] + sm.qk.sbe[d]) * scale);
                    }
                    *(u16x4*)&op[mt * 16 + quad * 4] = pk;
                }
            } else {
#pragma unroll
                for (int mt = 0; mt < 4; mt++)
#pragma unroll
                    for (int reg = 0; reg < 4; reg++) {
                        int d = mt * 16 + quad * 4 + reg;
                        a.vn[((size_t)b * EE + h * 64 + d) * 1024 + l] =
                            f2bu((vbuf[mt * 4 + reg] - mean) * r * sm.qk.sg[d] + sm.qk.sbe[d]);
                    }
            }
        }
    }
}

// ---------------------------------------------------------------------------
// Phase 3 body: QK^T once -> P = exp2(q'.k) (bf16, zero s-tail), l_s accum,
// fold 1/l_s in-place into vn.  vb decodes grid (16, NH, NB).
// ---------------------------------------------------------------------------
__device__ void stats_body(int vb, const KArgs& a, SMem& sm) {
    int gx = vb & 15, rem = vb >> 4;
    int h = rem & 15, b = rem >> 4;
    int s0 = gx * 64;
    int Sc = a.cntK[b], Tc = a.cntQ[b];
    if (s0 >= Sc) return;
    int tid = threadIdx.x;
    int w = tid >> 6, lane = tid & 63, quad = lane >> 4, l16 = lane & 15;
    int head = b * NH + h;
    const u16* kp = a.kc + (size_t)head * SS * DHH;
    const u16* qp = a.qc + (size_t)head * TT * DHH;
    u16* Pb = a.P + (size_t)head * TT * SS;
    stage_tile<64>(kp + (size_t)s0 * DHH, DHH, &sm.st.kt[0][0], w, lane);
    stage_tile<64>(qp, DHH, &sm.st.qt[0][0][0], w, lane);
    __syncthreads();
    float rl[4][4] = {};
    int cur = 0;
    for (int t0 = 0; t0 < Tc; t0 += 64, cur ^= 1) {
        if (t0 + 64 < Tc)
            stage_tile<64>(qp + (size_t)(t0 + 64) * DHH, DHH, &sm.st.qt[cur ^ 1][0][0], w, lane);
        f32x4 acc[4] = {};
#pragma unroll
        for (int ks = 0; ks < 64; ks += 32) {
            short8 bf = *(const short8*)swz_ptr(&sm.st.qt[cur][0][0], w * 16 + l16, ks + quad * 8);
#pragma unroll
            for (int mt = 0; mt < 4; mt++) {
                short8 af = *(const short8*)swz_ptr(&sm.st.kt[0][0], mt * 16 + l16, ks + quad * 8);
                acc[mt] = MFMA16(af, bf, acc[mt]);
            }
        }
        int tcol = t0 + w * 16 + l16;
        int tok = tcol < Tc;
#pragma unroll
        for (int mt = 0; mt < 4; mt++) {
            u16x4 pk;
#pragma unroll
            for (int reg = 0; reg < 4; reg++) {
                int sl = s0 + mt * 16 + quad * 4 + reg;
                float e = EXP2(acc[mt][reg]);
                if (tok) rl[mt][reg] += e;
                pk[reg] = (sl < Sc) ? f2bu(e) : (u16)0;
            }
            *(u16x4*)&Pb[(size_t)tcol * SS + s0 + mt * 16 + quad * 4] = pk;
        }
        __syncthreads();
    }
#pragma unroll
    for (int mt = 0; mt < 4; mt++) {
#pragma unroll
        for (int reg = 0; reg < 4; reg++) {
            float v = rl[mt][reg];
            v += __shfl_xor(v, 1); v += __shfl_xor(v, 2);
            v += __shfl_xor(v, 4); v += __shfl_xor(v, 8);
            if (l16 == 0) sm.st.lp[w][mt * 16 + quad * 4 + reg] = v;
        }
    }
    __syncthreads();
    {   // fold 1/l_s into vn in-place (this block owns s-rows [s0,s0+64) of h)
        int so = tid & 63, dg = tid >> 6;
        int s = s0 + so;
        float lv = sm.st.lp[0][so] + sm.st.lp[1][so] + sm.st.lp[2][so] + sm.st.lp[3][so];
        float wsc = (lv > 0.f) ? (1.f / lv) : 0.f;
        u16* vrow = a.vn + ((size_t)b * EE + h * 64) * SS;
        int live = s < Sc;
#pragma unroll
        for (int i = 0; i < 16; i++) {
            int d = dg * 16 + i;
            size_t ad = (size_t)d * SS + s;
            vrow[ad] = live ? f2bu(bu2f(vrow[ad]) * wsc) : (u16)0;
        }
    }
}

// ---------------------------------------------------------------------------
// Phase 4 body: PV as pure GEMM over K=ceil64(Sc) -> dense compact ac.
// vb decodes grid (16, NH, NB).
// ---------------------------------------------------------------------------
__device__ void pv_body(int vb, const KArgs& a, SMem& sm) {
    int gx = vb & 15, rem = vb >> 4;
    int h = rem & 15, b = rem >> 4;
    int t0 = gx * 64;
    int Tc = a.cntQ[b], Sc = a.cntK[b];
    if (t0 >= Tc) return;
    int Kc = (Sc + 63) & ~63;
    int tid = threadIdx.x;
    int w = tid >> 6, lane = tid & 63, quad = lane >> 4, l16 = lane & 15;
    int head = b * NH + h;
    const u16* vp = a.vn + ((size_t)head * DHH) * SS;
    const u16* Pb = a.P + (size_t)head * TT * SS + (size_t)t0 * SS;
    f32x4 oacc[4] = {};
    if (Kc > 0) {
        stage_tile<64>(vp, SS, &sm.pv.at[0][0][0], w, lane);
        stage_tile<64>(Pb, SS, &sm.pv.bt[0][0][0], w, lane);
        __syncthreads();
        int cur = 0;
        for (int k0 = 0; k0 < Kc; k0 += 64, cur ^= 1) {
            int kn = k0 + 64;
            if (kn < Kc) {
                stage_tile<64>(vp + kn, SS, &sm.pv.at[cur ^ 1][0][0], w, lane);
                stage_tile<64>(Pb + kn, SS, &sm.pv.bt[cur ^ 1][0][0], w, lane);
            }
#pragma unroll
            for (int ks = 0; ks < 64; ks += 32) {
                short8 bf = *(const short8*)swz_ptr(&sm.pv.bt[cur][0][0], w * 16 + l16, ks + quad * 8);
#pragma unroll
                for (int mt = 0; mt < 4; mt++) {
                    short8 af = *(const short8*)swz_ptr(&sm.pv.at[cur][0][0], mt * 16 + l16, ks + quad * 8);
                    oacc[mt] = MFMA16(af, bf, oacc[mt]);
                }
            }
            __syncthreads();
        }
    }
    int tl = w * 16 + l16;
#pragma unroll
    for (int mt = 0; mt < 4; mt++) {
        u16x4 pk;
#pragma unroll
        for (int reg = 0; reg < 4; reg++) pk[reg] = f2bu(oacc[mt][reg]);
        *(u16x4*)&sm.pv.pt[tl][mt * 16 + quad * 4] = pk;
    }
    __syncthreads();
#pragma unroll
    for (int i = 0; i < 2; i++) {
        int id = tid * 2 + i;
        int r = id >> 3, c = (id & 7) * 8;
        if (t0 + r < Tc)
            *(u16x8*)&a.ac[((size_t)b * TT + t0 + r) * EE + h * 64 + c] =
                *(const u16x8*)&sm.pv.pt[r][c];
    }
}

// ---------------------------------------------------------------------------
// Phase 5 body: o-proj (+bias +f32 residual), scatter via tIdx.
// vb decodes grid (8, 16, NB).
// ---------------------------------------------------------------------------
__device__ void po_body(int vb, const KArgs& a, SMem& sm) {
    int gx = vb & 7, rem = vb >> 3;
    int gy = rem & 15, b = rem >> 4;
    int o0 = gx * 128, l0 = gy * 64;
    int Tc = a.cntQ[b];
    if (l0 >= Tc) return;
    int tid = threadIdx.x;
    int w = tid >> 6, lane = tid & 63, quad = lane >> 4, l16 = lane & 15;
    int wm = w & 1, wn = w >> 1;
    if (tid < 128) sm.po.sbias[tid] = a.obi[o0 + tid];
    if (tid < 64) sm.po.stre[tid] = a.tIdx[(size_t)b * 1024 + l0 + tid];
    f32x4 acc[4][2] = {};
    gemm_core(a.won, a.ac + (size_t)b * TT * EE, EE, o0, l0, sm.po.at, sm.po.bt, acc);
#pragma unroll
    for (int nt = 0; nt < 2; nt++) {
        int lcol = wn * 32 + nt * 16 + l16;
        int l = l0 + lcol;
        if (l < Tc) {
            int treal = sm.po.stre[lcol];
#pragma unroll
            for (int mt = 0; mt < 4; mt++)
#pragma unroll
                for (int reg = 0; reg < 4; reg++) {
                    int o = o0 + wm * 64 + mt * 16 + quad * 4 + reg;
                    size_t off = ((size_t)b * EE + o) * TT + treal;
                    a.outF[off] = acc[mt][nt][reg] + sm.po.sbias[wm * 64 + mt * 16 + quad * 4 + reg] + a.x[off];
                }
        }
    }
}

// ---------------------------------------------------------------------------
// The persistent mega-kernel: 5 phases, software grid barrier between.
// ---------------------------------------------------------------------------
__global__ __launch_bounds__(256, 2) void mega(KArgs a) {
    __shared__ SMem sm;
    int bid0 = blockIdx.x;

    for (int vb = bid0; vb < PREP_FILL_END; vb += GRID_BLKS) {
        prep_body(vb, a, sm);
        __syncthreads();
    }
    grid_barrier(0);
    for (int vb = bid0; vb < 24 * 16 * NB; vb += GRID_BLKS) {
        qkv_body(vb, a, sm);
        __syncthreads();
    }
    grid_barrier(1);
    for (int vb = bid0; vb < 16 * NH * NB; vb += GRID_BLKS) {
        stats_body(vb, a, sm);
        __syncthreads();
    }
    grid_barrier(2);
    for (int vb = bid0; vb < 16 * NH * NB; vb += GRID_BLKS) {
        pv_body(vb, a, sm);
        __syncthreads();
    }
    grid_barrier(3);
    for (int vb = bid0; vb < 8 * 16 * NB; vb += GRID_BLKS) {
        po_body(vb, a, sm);
        __syncthreads();
    }
}

// ---------------------------------------------------------------------------
extern "C" void kernel_launch(void* const* d_in, const int* in_sizes, int n_in,
                              void* d_out, int out_size, void* d_ws, size_t ws_size,
                              hipStream_t stream) {
    KArgs a;
    a.x        = (const float*)d_in[0];
    a.ctx      = (const float*)d_in[1];
    a.mask     = (const int*)d_in[2];
    a.mask_ctx = (const int*)d_in[3];
    a.qw  = (const float*)d_in[4];
    a.qb  = (const float*)d_in[5];
    a.kw  = (const float*)d_in[6];
    a.kb  = (const float*)d_in[7];
    a.vw  = (const float*)d_in[8];
    a.vbi = (const float*)d_in[9];
    a.ow  = (const float*)d_in[10];
    a.obi = (const float*)d_in[11];
    a.gq = (const float*)d_in[12];
    a.bq = (const float*)d_in[13];
    a.gk = (const float*)d_in[14];
    a.bk = (const float*)d_in[15];
    a.gv = (const float*)d_in[16];
    a.bv = (const float*)d_in[17];

    // workspace carve (~190 MB)
    u16* p = (u16*)d_ws;
    a.wqn = p; p += (size_t)EE * EE;
    a.wkn = p; p += (size_t)EE * CCH;
    a.wvn = p; p += (size_t)EE * CCH;
    a.won = p; p += (size_t)EE * EE;
    a.xc  = p; p += (size_t)NB * TT * EE;        // compact [b][pos][e]
    a.cc  = p; p += (size_t)NB * SS * CCH;       // compact [b][pos][c]
    a.vn  = p; p += (size_t)NB * EE * SS;        // LN'd V [b][h*64+d][pos]; 1/l folded in-place
    a.qc  = p; p += (size_t)NB * NH * TT * DHH;  // compact q [bh][pos][d]
    a.kc  = p; p += (size_t)NB * NH * SS * DHH;  // compact k [bh][pos][d]
    a.ac  = p; p += (size_t)NB * TT * EE;        // attn out compact [b][pos][e]
    a.P   = p; p += (size_t)NB * NH * TT * SS;   // exp2 scores [bh][t][s] (134 MB)
    a.tIdx = (int*)p;
    a.sIdx = a.tIdx + NB * 1024;
    a.cntQ = a.sIdx + NB * 1024;
    a.cntK = a.cntQ + NB;
    a.outF = (float*)d_out;

    mega<<<dim3(GRID_BLKS), dim3(256), 0, stream>>>(a);
}

// Round 6
// 421.264 us; speedup vs baseline: 1.2316x; 1.2316x over previous
//
#include <hip/hip_runtime.h>

// Problem constants (B=4, T=S=1024, E=1024, CTX=768, H=16, DH=64)
#define NB 4
#define TT 1024
#define SS 1024
#define EE 1024
#define CCH 768
#define NH 16
#define DHH 64
#define EPSF 1e-5f
// SCALE = 1024 // (16**0.5) = 256.  Fold 1/256 * log2(e) into q so that
// exp(score/256) == exp2(q'.k) with a single v_exp_f32.
#define QSCALE (1.4426950408889634f / 256.0f)

#define ATTN_BLKS 1024   // 4 blocks/CU x 256 CU, exact residency (LDS 33280 -> 4/CU)

typedef unsigned short u16;
typedef __attribute__((ext_vector_type(8))) short short8;       // MFMA A/B frag
typedef __attribute__((ext_vector_type(8))) unsigned short u16x8;
typedef __attribute__((ext_vector_type(4))) unsigned short u16x4;
typedef __attribute__((ext_vector_type(4))) float f32x4;        // MFMA C/D frag

__device__ __forceinline__ u16 f2bu(float f) {
    union { float f; unsigned u; } x; x.f = f;
    unsigned r = x.u + 0x7fffu + ((x.u >> 16) & 1u);
    return (u16)(r >> 16);
}
__device__ __forceinline__ float bu2f(u16 u) {
    union { unsigned u; float f; } x; x.u = ((unsigned)u) << 16; return x.f;
}

#if __has_builtin(__builtin_amdgcn_exp2f)
#define EXP2(x) __builtin_amdgcn_exp2f(x)
#else
#define EXP2(x) exp2f(x)
#endif

#define MFMA16(a, b, c) __builtin_amdgcn_mfma_f32_16x16x32_bf16((a), (b), (c), 0, 0, 0)

// ---------------------------------------------------------------------------
// Software grid barrier (proven correct incl. cross-XCD visibility in R4's
// mega-kernel run: passed absmax 0.0625).  Monotonic per-phase tickets are
// graph-replay-safe.  Residency proof for ATTN_BLKS=1024: LDS union 33280 B
// -> floor(160K/33280)=4 blocks/CU; __launch_bounds__(256,4) caps VGPR<=128
// -> 16 waves/CU OK; 4 x 256 CU = 1024.
// ---------------------------------------------------------------------------
__device__ unsigned int g_cnt[4];   // zero-initialized at module load

__device__ __forceinline__ void grid_barrier(int idx) {
    __syncthreads();
    if (threadIdx.x == 0) {
        __threadfence();   // release: L2 writeback for cross-XCD readers
        unsigned ticket = atomicAdd(&g_cnt[idx], 1u);
        unsigned target = (ticket / ATTN_BLKS + 1u) * ATTN_BLKS;
        while (atomicAdd(&g_cnt[idx], 0u) < target)
            __builtin_amdgcn_s_sleep(2);
        __threadfence();   // acquire: invalidate stale caches before reads
    }
    __syncthreads();
}

// ---------------------------------------------------------------------------
// Async global->LDS staging (16B/lane).  LDS tiles are LINEAR [R][64] u16
// (128B rows); content XOR-swizzled: logical (row, bytecol) lives at physical
// (row, bytecol ^ ((row&7)<<4)).  Swizzle applied on the GLOBAL source
// address (linear dest + inverse-swizzled source + swizzled read).
// ---------------------------------------------------------------------------
__device__ __forceinline__ void gload16(const void* g, void* l) {
    __builtin_amdgcn_global_load_lds(
        (const __attribute__((address_space(1))) void*)g,
        (__attribute__((address_space(3))) void*)l, 16, 0, 0);
}

template<int R>
__device__ __forceinline__ void stage_tile(
    const u16* __restrict__ g, int ldg, u16* lds, int w, int lane) {
    constexpr int PW = R / 32;               // insts per wave
    int r0 = lane >> 3;                      // row within 8-row group == row&7
    int cs = ((lane & 7) << 4) ^ (r0 << 4);  // swizzled source byte col
#pragma unroll
    for (int j = 0; j < PW; j++) {
        int inst = w * PW + j;
        const u16* src = g + (size_t)(inst * 8 + r0) * ldg + (cs >> 1);
        gload16(src, lds + inst * 512);
    }
}

__device__ __forceinline__ const u16* swz_ptr(const u16* tile, int row, int col) {
    int off = row * 128 + ((col * 2) ^ ((row & 7) << 4));
    return (const u16*)((const char*)tile + off);
}

// prep block-range offsets
#define PREP_WS_END   4096                  // 4 mats x 1024 rows
#define PREP_SCAN_END (PREP_WS_END + 8)     // 2 masks x 4 batches
#define PREP_TR_END   (PREP_SCAN_END + 1792) // 16 x 28 x 4 transpose tiles
#define PREP_FILL_END (PREP_TR_END + 4096)  // 4 batches x 1024 rows fill

// ---------------------------------------------------------------------------
// PREP mega-kernel (verified, unchanged from the 227us config)
// ---------------------------------------------------------------------------
__global__ __launch_bounds__(256) void prep(
    const float* __restrict__ qw, const float* __restrict__ kw,
    const float* __restrict__ vw, const float* __restrict__ ow,
    u16* __restrict__ wqn, u16* __restrict__ wkn,
    u16* __restrict__ wvn, u16* __restrict__ won,
    const float* __restrict__ x, const float* __restrict__ ctx,
    const int* __restrict__ mask, const int* __restrict__ mask_ctx,
    u16* __restrict__ xc, u16* __restrict__ cc,
    int* __restrict__ tIdx, int* __restrict__ sIdx,
    int* __restrict__ cntQ, int* __restrict__ cntK,
    float* __restrict__ outF) {
    __shared__ float tile[64][65];
    __shared__ int spos[64], smask[64], wtoti[4];
    __shared__ float sa[4], sb2[4], smean, srstd;
    int bid = blockIdx.x, tid = threadIdx.x;

    if (bid < PREP_WS_END) {
        int mat = bid >> 10, row = bid & 1023;
        const float* w = mat == 0 ? qw : (mat == 1 ? kw : (mat == 2 ? vw : ow));
        u16* wn = mat == 0 ? wqn : (mat == 1 ? wkn : (mat == 2 ? wvn : won));
        int I = (mat == 1 || mat == 2) ? CCH : EE;
        const float* wr = w + (size_t)row * I;
        int nv = I >> 8;
        float vals[4];
        float s = 0.f, s2 = 0.f;
        for (int j = 0; j < nv; j++) {
            float v = wr[tid + 256 * j];
            vals[j] = v; s += v; s2 += v * v;
        }
#pragma unroll
        for (int off = 32; off > 0; off >>= 1) { s += __shfl_down(s, off); s2 += __shfl_down(s2, off); }
        int wid = tid >> 6;
        if ((tid & 63) == 0) { sa[wid] = s; sb2[wid] = s2; }
        __syncthreads();
        if (tid == 0) {
            float ts = sa[0] + sa[1] + sa[2] + sa[3];
            float ts2 = sb2[0] + sb2[1] + sb2[2] + sb2[3];
            float mean = ts / (float)I;
            float var = ts2 / (float)I - mean * mean;
            smean = mean; srstd = rsqrtf(var + EPSF);
        }
        __syncthreads();
        float mean = smean, r = srstd;
        u16* wo = wn + (size_t)row * I;
        for (int j = 0; j < nv; j++) wo[tid + 256 * j] = f2bu((vals[j] - mean) * r);
        return;
    }
    if (bid < PREP_SCAN_END) {
        int t = bid - PREP_WS_END;
        int which = t & 1, b = t >> 1;
        const int* m = (which ? mask_ctx : mask) + b * 1024;
        int* idx = (which ? sIdx : tIdx) + b * 1024;
        int* cnt = (which ? cntK : cntQ) + b;
        int base = tid * 4;
        int v[4]; int s = 0;
#pragma unroll
        for (int i = 0; i < 4; i++) { v[i] = m[base + i] ? 1 : 0; s += v[i]; }
        int lane = tid & 63, wid = tid >> 6;
        int inc = s;
#pragma unroll
        for (int off = 1; off < 64; off <<= 1) {
            int o = __shfl_up(inc, off);
            if (lane >= off) inc += o;
        }
        if (lane == 63) wtoti[wid] = inc;
        __syncthreads();
        int woff = 0;
        for (int i = 0; i < wid; i++) woff += wtoti[i];
        int p = woff + inc - s;
#pragma unroll
        for (int i = 0; i < 4; i++) {
            if (v[i]) idx[p] = base + i;
            p += v[i];
        }
        if (tid == 255) *cnt = p;
        return;
    }
    if (bid < PREP_TR_END) {
        int t = bid - PREP_SCAN_END;
        int xb = t & 15; int rem = t >> 4;
        int yy = rem % 28, b = rem / 28;
        int mat = yy < 16 ? 0 : 1;
        int r0 = (mat == 0 ? yy : yy - 16) * 64;
        int R = mat == 0 ? EE : CCH;
        const float* in = mat == 0 ? x : ctx;
        const int* m = (mat == 0 ? mask : mask_ctx) + (size_t)b * 1024;
        u16* out = mat == 0 ? xc : cc;
        int c0 = xb * 64;
        const float* ip = in + (size_t)b * R * 1024;
        u16* op = out + (size_t)b * R * 1024;
#pragma unroll
        for (int mm = 0; mm < 16; mm++) {
            int id = tid + 256 * mm; int r = id >> 6, c = id & 63;
            tile[r][c] = ip[(size_t)(r0 + r) * 1024 + c0 + c];
        }
        int base = tid * 4;
        int v[4]; int s = 0;
#pragma unroll
        for (int i = 0; i < 4; i++) { v[i] = m[base + i] ? 1 : 0; s += v[i]; }
        int lane = tid & 63, wid = tid >> 6;
        int inc = s;
#pragma unroll
        for (int off = 1; off < 64; off <<= 1) {
            int o = __shfl_up(inc, off);
            if (lane >= off) inc += o;
        }
        if (lane == 63) wtoti[wid] = inc;
        __syncthreads();
        int woff = 0;
        for (int i = 0; i < wid; i++) woff += wtoti[i];
        int p = woff + inc - s;
#pragma unroll
        for (int i = 0; i < 4; i++) {
            int g = base + i;
            if (g >= c0 && g < c0 + 64) { spos[g - c0] = p; smask[g - c0] = v[i]; }
            p += v[i];
        }
        __syncthreads();
#pragma unroll
        for (int mm = 0; mm < 16; mm++) {
            int id = tid + 256 * mm; int rr = id >> 6, cc2 = id & 63;
            if (smask[rr])
                op[(size_t)spos[rr] * R + r0 + cc2] = f2bu(tile[cc2][rr]);
        }
        return;
    }
    {   // masked residual fill
        int f = bid - PREP_TR_END;
        int b = f >> 10, o = f & 1023;
        const float* xr = x + ((size_t)b * EE + o) * TT;
        float* orow = outF + ((size_t)b * EE + o) * TT;
        const int* mrow = mask + (size_t)b * TT;
        int4 mv = ((const int4*)mrow)[tid];
        float4 xv = ((const float4*)xr)[tid];
        int t4 = tid * 4;
        if (!mv.x) orow[t4 + 0] = xv.x;
        if (!mv.y) orow[t4 + 1] = xv.y;
        if (!mv.z) orow[t4 + 2] = xv.z;
        if (!mv.w) orow[t4 + 3] = xv.w;
    }
}

// ---------------------------------------------------------------------------
// GEMM core: 128x64 tile, 4 waves, each a 64x32 quadrant (4x2 16x16x32 frags).
// global_load_lds staging, double-buffered LDS, one barrier per 64-K-step.
// ---------------------------------------------------------------------------
__device__ __forceinline__ void gemm_core(
    const u16* __restrict__ A, const u16* __restrict__ Bp, int I,
    int o0, int l0, u16 (*at)[128][64], u16 (*bt)[64][64], f32x4 (&acc)[4][2]) {
    int tid = threadIdx.x;
    int w = tid >> 6, lane = tid & 63, quad = lane >> 4, l16 = lane & 15;
    int wm = w & 1, wn = w >> 1;
    const u16* Ab = A + (size_t)o0 * I;
    const u16* Bb = Bp + (size_t)l0 * I;
    stage_tile<128>(Ab, I, &at[0][0][0], w, lane);
    stage_tile<64>(Bb, I, &bt[0][0][0], w, lane);
    __syncthreads();
    int cur = 0;
    for (int k0 = 0; k0 < I; k0 += 64, cur ^= 1) {
        int kn = k0 + 64;
        if (kn < I) {
            stage_tile<128>(Ab + kn, I, &at[cur ^ 1][0][0], w, lane);
            stage_tile<64>(Bb + kn, I, &bt[cur ^ 1][0][0], w, lane);
        }
#pragma unroll
        for (int ks = 0; ks < 64; ks += 32) {
            short8 af[4], bf[2];
#pragma unroll
            for (int i = 0; i < 4; i++)
                af[i] = *(const short8*)swz_ptr(&at[cur][0][0], wm * 64 + i * 16 + l16, ks + quad * 8);
#pragma unroll
            for (int j = 0; j < 2; j++)
                bf[j] = *(const short8*)swz_ptr(&bt[cur][0][0], wn * 32 + j * 16 + l16, ks + quad * 8);
#pragma unroll
            for (int mt = 0; mt < 4; mt++)
#pragma unroll
                for (int nt = 0; nt < 2; nt++)
                    acc[mt][nt] = MFMA16(af[mt], bf[nt], acc[mt][nt]);
        }
        __syncthreads();
    }
}

// ---------------------------------------------------------------------------
// Fused q/k/v projections (verified, unchanged).  grid (24, 16, NB).
// ---------------------------------------------------------------------------
__global__ __launch_bounds__(256) void proj_qkv(
    const u16* __restrict__ wq, const u16* __restrict__ wk, const u16* __restrict__ wv,
    const u16* __restrict__ xc, const u16* __restrict__ cc,
    const float* __restrict__ qb, const float* __restrict__ kb, const float* __restrict__ vbi,
    const int* __restrict__ cntQ, const int* __restrict__ cntK,
    const float* __restrict__ gq, const float* __restrict__ bq,
    const float* __restrict__ gk, const float* __restrict__ bk,
    const float* __restrict__ gv, const float* __restrict__ bv,
    u16* __restrict__ qc, u16* __restrict__ kc, u16* __restrict__ vn) {
    int mat = blockIdx.x >> 3;
    int o0 = (blockIdx.x & 7) * 128;
    int l0 = blockIdx.y * 64;
    int b = blockIdx.z;
    int limit = (mat == 0) ? cntQ[b] : cntK[b];
    if (l0 >= limit) return;
    __shared__ u16 at[2][128][64];
    __shared__ u16 bt[2][64][64];
    __shared__ float sg[64], sbe[64], sbias[128];
    int tid = threadIdx.x;
    int w = tid >> 6, lane = tid & 63, quad = lane >> 4, l16 = lane & 15;
    int wm = w & 1, wn = w >> 1;
    const u16* A = mat == 0 ? wq : (mat == 1 ? wk : wv);
    const u16* BT = mat == 0 ? xc : cc;
    const float* bias = mat == 0 ? qb : (mat == 1 ? kb : vbi);
    int I = mat == 0 ? EE : CCH;
    if (tid < 64) {
        const float* gsrc = mat == 0 ? gq : (mat == 1 ? gk : gv);
        const float* bsrc = mat == 0 ? bq : (mat == 1 ? bk : bv);
        sg[tid] = gsrc[tid];
        sbe[tid] = bsrc[tid];
    }
    if (tid < 128) sbias[tid] = bias[o0 + tid];

    f32x4 acc[4][2] = {};
    gemm_core(A, BT + (size_t)b * 1024 * I, I, o0, l0, at, bt, acc);

    float scale = mat == 0 ? QSCALE : 1.0f;
    int h = (o0 >> 6) + wm;
    int bh = b * NH + h;
#pragma unroll
    for (int nt = 0; nt < 2; nt++) {
        int l = l0 + wn * 32 + nt * 16 + l16;
        float vbuf[16];
        float s = 0.f;
#pragma unroll
        for (int mt = 0; mt < 4; mt++)
#pragma unroll
            for (int reg = 0; reg < 4; reg++) {
                float v = acc[mt][nt][reg] + sbias[wm * 64 + mt * 16 + quad * 4 + reg];
                vbuf[mt * 4 + reg] = v; s += v;
            }
        s += __shfl_xor(s, 16); s += __shfl_xor(s, 32);
        float mean = s * (1.f / 64);
        float s2 = 0.f;
#pragma unroll
        for (int i = 0; i < 16; i++) { float dv = vbuf[i] - mean; s2 += dv * dv; }
        s2 += __shfl_xor(s2, 16); s2 += __shfl_xor(s2, 32);
        float r = rsqrtf(s2 * (1.f / 64) + EPSF);
        if (l < limit) {
            if (mat < 2) {
                u16* outT = mat == 0 ? qc : kc;
                u16* op = outT + ((size_t)bh * 1024 + l) * 64;
#pragma unroll
                for (int mt = 0; mt < 4; mt++) {
                    u16x4 pk;
#pragma unroll
                    for (int reg = 0; reg < 4; reg++) {
                        int d = mt * 16 + quad * 4 + reg;
                        pk[reg] = f2bu(((vbuf[mt * 4 + reg] - mean) * r * sg[d] + sbe[d]) * scale);
                    }
                    *(u16x4*)&op[mt * 16 + quad * 4] = pk;
                }
            } else {
#pragma unroll
                for (int mt = 0; mt < 4; mt++)
#pragma unroll
                    for (int reg = 0; reg < 4; reg++) {
                        int d = mt * 16 + quad * 4 + reg;
                        vn[((size_t)b * EE + h * 64 + d) * 1024 + l] =
                            f2bu((vbuf[mt * 4 + reg] - mean) * r * sg[d] + sbe[d]);
                    }
            }
        }
    }
}

// ---------------------------------------------------------------------------
// attn_all: stats + PV + o-proj in ONE dispatch with 2 internal grid barriers.
// 1024 blocks, ONE item per block per phase (no grid-stride serialization).
// LDS union 33280 B -> exactly 4 blocks/CU -> all 1024 co-resident.
// Phase S: per (s-tile,h,b): P = exp2(q'.k), l_s accum, fold 1/l_s into vn.
// Phase P: per (t-tile,h,b): pure GEMM out[d][t] = sum_s vn'[d][s] P[t][s].
// Phase O: per (o-64tile, l-64tile, b): o-proj + bias + f32 residual scatter.
// ---------------------------------------------------------------------------
union ASMem {
    struct {
        u16 kt[64][64];
        u16 qt[2][64][64];
        float lp[4][64];
    } st;                                   // 25600 B
    struct {
        u16 at[2][64][64];                  // vn' tiles; pt aliases at[0] after loop
        u16 bt[2][64][64];                  // P tiles
    } pv;                                   // 32768 B
    struct {
        u16 at[2][64][64];
        u16 bt[2][64][64];
        float sbias[64];
        int stre[64];
    } po;                                   // 33280 B
};

__global__ __launch_bounds__(256, 4) void attn_all(
    const u16* __restrict__ qc, const u16* __restrict__ kc,
    u16* __restrict__ vn, u16* __restrict__ P, u16* __restrict__ ac,
    const u16* __restrict__ won, const float* __restrict__ obi,
    const int* __restrict__ tIdx,
    const int* __restrict__ cntQ, const int* __restrict__ cntK,
    const float* __restrict__ x, float* __restrict__ out) {
    __shared__ ASMem sm;
    int bid = blockIdx.x, tid = threadIdx.x;
    int w = tid >> 6, lane = tid & 63, quad = lane >> 4, l16 = lane & 15;
    int gx = bid & 15, gy = (bid >> 4) & 15, b = bid >> 8;

    // ================= phase S: stats =================
    {
        int s0 = gx * 64, h = gy;
        int Sc = cntK[b], Tc = cntQ[b];
        if (s0 < Sc) {
            int head = b * NH + h;
            const u16* kp = kc + (size_t)head * SS * DHH;
            const u16* qp = qc + (size_t)head * TT * DHH;
            u16* Pb = P + (size_t)head * TT * SS;
            stage_tile<64>(kp + (size_t)s0 * DHH, DHH, &sm.st.kt[0][0], w, lane);
            stage_tile<64>(qp, DHH, &sm.st.qt[0][0][0], w, lane);
            __syncthreads();
            float rl[4][4] = {};
            int cur = 0;
            for (int t0 = 0; t0 < Tc; t0 += 64, cur ^= 1) {
                if (t0 + 64 < Tc)
                    stage_tile<64>(qp + (size_t)(t0 + 64) * DHH, DHH, &sm.st.qt[cur ^ 1][0][0], w, lane);
                f32x4 acc[4] = {};
#pragma unroll
                for (int ks = 0; ks < 64; ks += 32) {
                    short8 bf = *(const short8*)swz_ptr(&sm.st.qt[cur][0][0], w * 16 + l16, ks + quad * 8);
#pragma unroll
                    for (int mt = 0; mt < 4; mt++) {
                        short8 af = *(const short8*)swz_ptr(&sm.st.kt[0][0], mt * 16 + l16, ks + quad * 8);
                        acc[mt] = MFMA16(af, bf, acc[mt]);
                    }
                }
                int tcol = t0 + w * 16 + l16;
                int tok = tcol < Tc;
#pragma unroll
                for (int mt = 0; mt < 4; mt++) {
                    u16x4 pk;
#pragma unroll
                    for (int reg = 0; reg < 4; reg++) {
                        int sl = s0 + mt * 16 + quad * 4 + reg;
                        float e = EXP2(acc[mt][reg]);
                        if (tok) rl[mt][reg] += e;
                        pk[reg] = (sl < Sc) ? f2bu(e) : (u16)0;
                    }
                    *(u16x4*)&Pb[(size_t)tcol * SS + s0 + mt * 16 + quad * 4] = pk;
                }
                __syncthreads();
            }
#pragma unroll
            for (int mt = 0; mt < 4; mt++) {
#pragma unroll
                for (int reg = 0; reg < 4; reg++) {
                    float v = rl[mt][reg];
                    v += __shfl_xor(v, 1); v += __shfl_xor(v, 2);
                    v += __shfl_xor(v, 4); v += __shfl_xor(v, 8);
                    if (l16 == 0) sm.st.lp[w][mt * 16 + quad * 4 + reg] = v;
                }
            }
            __syncthreads();
            {   // fold 1/l_s into vn in-place
                int so = tid & 63, dg = tid >> 6;
                int s = s0 + so;
                float lv = sm.st.lp[0][so] + sm.st.lp[1][so] + sm.st.lp[2][so] + sm.st.lp[3][so];
                float wsc = (lv > 0.f) ? (1.f / lv) : 0.f;
                u16* vrow = vn + ((size_t)b * EE + h * 64) * SS;
                int live = s < Sc;
#pragma unroll
                for (int i = 0; i < 16; i++) {
                    int d = dg * 16 + i;
                    size_t ad = (size_t)d * SS + s;
                    vrow[ad] = live ? f2bu(bu2f(vrow[ad]) * wsc) : (u16)0;
                }
            }
        }
    }
    grid_barrier(0);
    // ================= phase P: PV GEMM =================
    {
        int t0 = gx * 64, h = gy;
        int Tc = cntQ[b], Sc = cntK[b];
        if (t0 < Tc) {
            int Kc = (Sc + 63) & ~63;
            int head = b * NH + h;
            const u16* vp = vn + ((size_t)head * DHH) * SS;
            const u16* Pb = P + (size_t)head * TT * SS + (size_t)t0 * SS;
            f32x4 oacc[4] = {};
            if (Kc > 0) {
                stage_tile<64>(vp, SS, &sm.pv.at[0][0][0], w, lane);
                stage_tile<64>(Pb, SS, &sm.pv.bt[0][0][0], w, lane);
                __syncthreads();
                int cur = 0;
                for (int k0 = 0; k0 < Kc; k0 += 64, cur ^= 1) {
                    int kn = k0 + 64;
                    if (kn < Kc) {
                        stage_tile<64>(vp + kn, SS, &sm.pv.at[cur ^ 1][0][0], w, lane);
                        stage_tile<64>(Pb + kn, SS, &sm.pv.bt[cur ^ 1][0][0], w, lane);
                    }
#pragma unroll
                    for (int ks = 0; ks < 64; ks += 32) {
                        short8 bf = *(const short8*)swz_ptr(&sm.pv.bt[cur][0][0], w * 16 + l16, ks + quad * 8);
#pragma unroll
                        for (int mt = 0; mt < 4; mt++) {
                            short8 af = *(const short8*)swz_ptr(&sm.pv.at[cur][0][0], mt * 16 + l16, ks + quad * 8);
                            oacc[mt] = MFMA16(af, bf, oacc[mt]);
                        }
                    }
                    __syncthreads();
                }
            }
            // out-transpose staging aliased over at (done with all LDS reads)
            u16 (*pt)[72] = (u16(*)[72])&sm.pv.at[0][0][0];
            int tl = w * 16 + l16;
#pragma unroll
            for (int mt = 0; mt < 4; mt++) {
                u16x4 pk;
#pragma unroll
                for (int reg = 0; reg < 4; reg++) pk[reg] = f2bu(oacc[mt][reg]);
                *(u16x4*)&pt[tl][mt * 16 + quad * 4] = pk;
            }
            __syncthreads();
#pragma unroll
            for (int i = 0; i < 2; i++) {
                int id = tid * 2 + i;
                int r = id >> 3, c = (id & 7) * 8;
                if (t0 + r < Tc)
                    *(u16x8*)&ac[((size_t)b * TT + t0 + r) * EE + gy * 64 + c] =
                        *(const u16x8*)&pt[r][c];
            }
        }
    }
    grid_barrier(1);
    // ================= phase O: o-proj 64x64 =================
    {
        int o0 = gx * 64, l0 = gy * 64;
        int Tc = cntQ[b];
        if (l0 < Tc) {
            if (tid < 64) {
                sm.po.sbias[tid] = obi[o0 + tid];
                sm.po.stre[tid] = tIdx[(size_t)b * 1024 + l0 + tid];
            }
            const u16* Ab = won + (size_t)o0 * EE;
            const u16* Bb = ac + (size_t)b * TT * EE + (size_t)l0 * EE;
            f32x4 acc[4] = {};
            stage_tile<64>(Ab, EE, &sm.po.at[0][0][0], w, lane);
            stage_tile<64>(Bb, EE, &sm.po.bt[0][0][0], w, lane);
            __syncthreads();
            int cur = 0;
            for (int k0 = 0; k0 < EE; k0 += 64, cur ^= 1) {
                int kn = k0 + 64;
                if (kn < EE) {
                    stage_tile<64>(Ab + kn, EE, &sm.po.at[cur ^ 1][0][0], w, lane);
                    stage_tile<64>(Bb + kn, EE, &sm.po.bt[cur ^ 1][0][0], w, lane);
                }
#pragma unroll
                for (int ks = 0; ks < 64; ks += 32) {
                    short8 bf = *(const short8*)swz_ptr(&sm.po.bt[cur][0][0], w * 16 + l16, ks + quad * 8);
#pragma unroll
                    for (int mt = 0; mt < 4; mt++) {
                        short8 af = *(const short8*)swz_ptr(&sm.po.at[cur][0][0], mt * 16 + l16, ks + quad * 8);
                        acc[mt] = MFMA16(af, bf, acc[mt]);
                    }
                }
                __syncthreads();
            }
            int l = l0 + w * 16 + l16;
            if (l < Tc) {
                int treal = sm.po.stre[w * 16 + l16];
#pragma unroll
                for (int mt = 0; mt < 4; mt++)
#pragma unroll
                    for (int reg = 0; reg < 4; reg++) {
                        int o = o0 + mt * 16 + quad * 4 + reg;
                        size_t off = ((size_t)b * EE + o) * TT + treal;
                        out[off] = acc[mt][reg] + sm.po.sbias[mt * 16 + quad * 4 + reg] + x[off];
                    }
            }
        }
    }
}

// ---------------------------------------------------------------------------
extern "C" void kernel_launch(void* const* d_in, const int* in_sizes, int n_in,
                              void* d_out, int out_size, void* d_ws, size_t ws_size,
                              hipStream_t stream) {
    const float* x        = (const float*)d_in[0];
    const float* ctx      = (const float*)d_in[1];
    const int*   mask     = (const int*)d_in[2];
    const int*   mask_ctx = (const int*)d_in[3];
    const float* qw  = (const float*)d_in[4];
    const float* qbi = (const float*)d_in[5];
    const float* kw  = (const float*)d_in[6];
    const float* kbi = (const float*)d_in[7];
    const float* vw  = (const float*)d_in[8];
    const float* vbi = (const float*)d_in[9];
    const float* ow  = (const float*)d_in[10];
    const float* obi = (const float*)d_in[11];
    const float* gq = (const float*)d_in[12];
    const float* bq = (const float*)d_in[13];
    const float* gk = (const float*)d_in[14];
    const float* bk = (const float*)d_in[15];
    const float* gv = (const float*)d_in[16];
    const float* bv = (const float*)d_in[17];

    // workspace carve (~190 MB)
    u16* p = (u16*)d_ws;
    u16* wqn = p; p += (size_t)EE * EE;
    u16* wkn = p; p += (size_t)EE * CCH;
    u16* wvn = p; p += (size_t)EE * CCH;
    u16* won = p; p += (size_t)EE * EE;
    u16* xc  = p; p += (size_t)NB * TT * EE;        // compact [b][pos][e]
    u16* cc  = p; p += (size_t)NB * SS * CCH;       // compact [b][pos][c]
    u16* vn  = p; p += (size_t)NB * EE * SS;        // LN'd V [b][h*64+d][pos]; 1/l folded in-place
    u16* qc  = p; p += (size_t)NB * NH * TT * DHH;  // compact q [bh][pos][d]
    u16* kc  = p; p += (size_t)NB * NH * SS * DHH;  // compact k [bh][pos][d]
    u16* ac  = p; p += (size_t)NB * TT * EE;        // attn out compact [b][pos][e]
    u16* P   = p; p += (size_t)NB * NH * TT * SS;   // exp2 scores [bh][t][s] (134 MB)
    int* tIdx = (int*)p;
    int* sIdx = tIdx + NB * 1024;
    int* cntQ = sIdx + NB * 1024;
    int* cntK = cntQ + NB;

    // 1) prep: WS-norm + mask scan + compacting transpose + masked resid fill
    prep<<<PREP_FILL_END, 256, 0, stream>>>(
        qw, kw, vw, ow, wqn, wkn, wvn, won, x, ctx, mask, mask_ctx,
        xc, cc, tIdx, sIdx, cntQ, cntK, (float*)d_out);

    // 2) fused q/k/v projections over compact columns + LN epilogue for q,k,v
    proj_qkv<<<dim3(24, 16, NB), 256, 0, stream>>>(
        wqn, wkn, wvn, xc, cc, qbi, kbi, vbi, cntQ, cntK,
        gq, bq, gk, bk, gv, bv, qc, kc, vn);

    // 3) stats + PV + o-proj fused with 2 software grid barriers (1024 blocks,
    //    exactly 4/CU co-resident, one item per block per phase)
    attn_all<<<dim3(ATTN_BLKS), dim3(256), 0, stream>>>(
        qc, kc, vn, P, ac, won, obi, tIdx, cntQ, cntK, x, (float*)d_out);
}

// Round 7
// 306.090 us; speedup vs baseline: 1.6950x; 1.3763x over previous
//
#include <hip/hip_runtime.h>

// Problem constants (B=4, T=S=1024, E=1024, CTX=768, H=16, DH=64)
#define NB 4
#define TT 1024
#define SS 1024
#define EE 1024
#define CCH 768
#define NH 16
#define DHH 64
#define EPSF 1e-5f
// SCALE = 1024 // (16**0.5) = 256.  Fold 1/256 * log2(e) into q so that
// exp(score/256) == exp2(q'.k) with a single v_exp_f32.
#define QSCALE (1.4426950408889634f / 256.0f)

typedef unsigned short u16;
typedef __attribute__((ext_vector_type(8))) short short8;       // MFMA A/B frag
typedef __attribute__((ext_vector_type(8))) unsigned short u16x8;
typedef __attribute__((ext_vector_type(4))) unsigned short u16x4;
typedef __attribute__((ext_vector_type(4))) float f32x4;        // MFMA C/D frag

__device__ __forceinline__ u16 f2bu(float f) {
    union { float f; unsigned u; } x; x.f = f;
    unsigned r = x.u + 0x7fffu + ((x.u >> 16) & 1u);
    return (u16)(r >> 16);
}
__device__ __forceinline__ float bu2f(u16 u) {
    union { unsigned u; float f; } x; x.u = ((unsigned)u) << 16; return x.f;
}

#if __has_builtin(__builtin_amdgcn_exp2f)
#define EXP2(x) __builtin_amdgcn_exp2f(x)
#else
#define EXP2(x) exp2f(x)
#endif

#define MFMA16(a, b, c) __builtin_amdgcn_mfma_f32_16x16x32_bf16((a), (b), (c), 0, 0, 0)

// ---------------------------------------------------------------------------
// Async global->LDS staging (16B/lane) -- used ONLY by prep/proj_qkv cores.
// LDS tiles LINEAR [R][64] u16; content XOR-swizzled via pre-swizzled global
// source (linear dest + inverse-swizzled source + swizzled read).
// ---------------------------------------------------------------------------
__device__ __forceinline__ void gload16(const void* g, void* l) {
    __builtin_amdgcn_global_load_lds(
        (const __attribute__((address_space(1))) void*)g,
        (__attribute__((address_space(3))) void*)l, 16, 0, 0);
}

template<int R>
__device__ __forceinline__ void stage_tile(
    const u16* __restrict__ g, int ldg, u16* lds, int w, int lane) {
    constexpr int PW = R / 32;               // insts per wave
    int r0 = lane >> 3;                      // row within 8-row group == row&7
    int cs = ((lane & 7) << 4) ^ (r0 << 4);  // swizzled source byte col
#pragma unroll
    for (int j = 0; j < PW; j++) {
        int inst = w * PW + j;
        const u16* src = g + (size_t)(inst * 8 + r0) * ldg + (cs >> 1);
        gload16(src, lds + inst * 512);
    }
}

__device__ __forceinline__ const u16* swz_ptr(const u16* tile, int row, int col) {
    int off = row * 128 + ((col * 2) ^ ((row & 7) << 4));
    return (const u16*)((const char*)tile + off);
}

// prep block-range offsets
#define PREP_WS_END   4096                  // 4 mats x 1024 rows
#define PREP_SCAN_END (PREP_WS_END + 8)     // 2 masks x 4 batches
#define PREP_TR_END   (PREP_SCAN_END + 1792) // 16 x 28 x 4 transpose tiles
#define PREP_FILL_END (PREP_TR_END + 4096)  // 4 batches x 1024 rows fill

// ---------------------------------------------------------------------------
// PREP mega-kernel (verified, unchanged)
// ---------------------------------------------------------------------------
__global__ __launch_bounds__(256) void prep(
    const float* __restrict__ qw, const float* __restrict__ kw,
    const float* __restrict__ vw, const float* __restrict__ ow,
    u16* __restrict__ wqn, u16* __restrict__ wkn,
    u16* __restrict__ wvn, u16* __restrict__ won,
    const float* __restrict__ x, const float* __restrict__ ctx,
    const int* __restrict__ mask, const int* __restrict__ mask_ctx,
    u16* __restrict__ xc, u16* __restrict__ cc,
    int* __restrict__ tIdx, int* __restrict__ sIdx,
    int* __restrict__ cntQ, int* __restrict__ cntK,
    float* __restrict__ outF) {
    __shared__ float tile[64][65];
    __shared__ int spos[64], smask[64], wtoti[4];
    __shared__ float sa[4], sb2[4], smean, srstd;
    int bid = blockIdx.x, tid = threadIdx.x;

    if (bid < PREP_WS_END) {
        int mat = bid >> 10, row = bid & 1023;
        const float* w = mat == 0 ? qw : (mat == 1 ? kw : (mat == 2 ? vw : ow));
        u16* wn = mat == 0 ? wqn : (mat == 1 ? wkn : (mat == 2 ? wvn : won));
        int I = (mat == 1 || mat == 2) ? CCH : EE;
        const float* wr = w + (size_t)row * I;
        int nv = I >> 8;
        float vals[4];
        float s = 0.f, s2 = 0.f;
        for (int j = 0; j < nv; j++) {
            float v = wr[tid + 256 * j];
            vals[j] = v; s += v; s2 += v * v;
        }
#pragma unroll
        for (int off = 32; off > 0; off >>= 1) { s += __shfl_down(s, off); s2 += __shfl_down(s2, off); }
        int wid = tid >> 6;
        if ((tid & 63) == 0) { sa[wid] = s; sb2[wid] = s2; }
        __syncthreads();
        if (tid == 0) {
            float ts = sa[0] + sa[1] + sa[2] + sa[3];
            float ts2 = sb2[0] + sb2[1] + sb2[2] + sb2[3];
            float mean = ts / (float)I;
            float var = ts2 / (float)I - mean * mean;
            smean = mean; srstd = rsqrtf(var + EPSF);
        }
        __syncthreads();
        float mean = smean, r = srstd;
        u16* wo = wn + (size_t)row * I;
        for (int j = 0; j < nv; j++) wo[tid + 256 * j] = f2bu((vals[j] - mean) * r);
        return;
    }
    if (bid < PREP_SCAN_END) {
        int t = bid - PREP_WS_END;
        int which = t & 1, b = t >> 1;
        const int* m = (which ? mask_ctx : mask) + b * 1024;
        int* idx = (which ? sIdx : tIdx) + b * 1024;
        int* cnt = (which ? cntK : cntQ) + b;
        int base = tid * 4;
        int v[4]; int s = 0;
#pragma unroll
        for (int i = 0; i < 4; i++) { v[i] = m[base + i] ? 1 : 0; s += v[i]; }
        int lane = tid & 63, wid = tid >> 6;
        int inc = s;
#pragma unroll
        for (int off = 1; off < 64; off <<= 1) {
            int o = __shfl_up(inc, off);
            if (lane >= off) inc += o;
        }
        if (lane == 63) wtoti[wid] = inc;
        __syncthreads();
        int woff = 0;
        for (int i = 0; i < wid; i++) woff += wtoti[i];
        int p = woff + inc - s;
#pragma unroll
        for (int i = 0; i < 4; i++) {
            if (v[i]) idx[p] = base + i;
            p += v[i];
        }
        if (tid == 255) *cnt = p;
        return;
    }
    if (bid < PREP_TR_END) {
        int t = bid - PREP_SCAN_END;
        int xb = t & 15; int rem = t >> 4;
        int yy = rem % 28, b = rem / 28;
        int mat = yy < 16 ? 0 : 1;
        int r0 = (mat == 0 ? yy : yy - 16) * 64;
        int R = mat == 0 ? EE : CCH;
        const float* in = mat == 0 ? x : ctx;
        const int* m = (mat == 0 ? mask : mask_ctx) + (size_t)b * 1024;
        u16* out = mat == 0 ? xc : cc;
        int c0 = xb * 64;
        const float* ip = in + (size_t)b * R * 1024;
        u16* op = out + (size_t)b * R * 1024;
#pragma unroll
        for (int mm = 0; mm < 16; mm++) {
            int id = tid + 256 * mm; int r = id >> 6, c = id & 63;
            tile[r][c] = ip[(size_t)(r0 + r) * 1024 + c0 + c];
        }
        int base = tid * 4;
        int v[4]; int s = 0;
#pragma unroll
        for (int i = 0; i < 4; i++) { v[i] = m[base + i] ? 1 : 0; s += v[i]; }
        int lane = tid & 63, wid = tid >> 6;
        int inc = s;
#pragma unroll
        for (int off = 1; off < 64; off <<= 1) {
            int o = __shfl_up(inc, off);
            if (lane >= off) inc += o;
        }
        if (lane == 63) wtoti[wid] = inc;
        __syncthreads();
        int woff = 0;
        for (int i = 0; i < wid; i++) woff += wtoti[i];
        int p = woff + inc - s;
#pragma unroll
        for (int i = 0; i < 4; i++) {
            int g = base + i;
            if (g >= c0 && g < c0 + 64) { spos[g - c0] = p; smask[g - c0] = v[i]; }
            p += v[i];
        }
        __syncthreads();
#pragma unroll
        for (int mm = 0; mm < 16; mm++) {
            int id = tid + 256 * mm; int rr = id >> 6, cc2 = id & 63;
            if (smask[rr])
                op[(size_t)spos[rr] * R + r0 + cc2] = f2bu(tile[cc2][rr]);
        }
        return;
    }
    {   // masked residual fill
        int f = bid - PREP_TR_END;
        int b = f >> 10, o = f & 1023;
        const float* xr = x + ((size_t)b * EE + o) * TT;
        float* orow = outF + ((size_t)b * EE + o) * TT;
        const int* mrow = mask + (size_t)b * TT;
        int4 mv = ((const int4*)mrow)[tid];
        float4 xv = ((const float4*)xr)[tid];
        int t4 = tid * 4;
        if (!mv.x) orow[t4 + 0] = xv.x;
        if (!mv.y) orow[t4 + 1] = xv.y;
        if (!mv.z) orow[t4 + 2] = xv.z;
        if (!mv.w) orow[t4 + 3] = xv.w;
    }
}

// ---------------------------------------------------------------------------
// GEMM core (verified, used only by proj_qkv): 128x64 tile, gll dbuf.
// ---------------------------------------------------------------------------
__device__ __forceinline__ void gemm_core(
    const u16* __restrict__ A, const u16* __restrict__ Bp, int I,
    int o0, int l0, u16 (*at)[128][64], u16 (*bt)[64][64], f32x4 (&acc)[4][2]) {
    int tid = threadIdx.x;
    int w = tid >> 6, lane = tid & 63, quad = lane >> 4, l16 = lane & 15;
    int wm = w & 1, wn = w >> 1;
    const u16* Ab = A + (size_t)o0 * I;
    const u16* Bb = Bp + (size_t)l0 * I;
    stage_tile<128>(Ab, I, &at[0][0][0], w, lane);
    stage_tile<64>(Bb, I, &bt[0][0][0], w, lane);
    __syncthreads();
    int cur = 0;
    for (int k0 = 0; k0 < I; k0 += 64, cur ^= 1) {
        int kn = k0 + 64;
        if (kn < I) {
            stage_tile<128>(Ab + kn, I, &at[cur ^ 1][0][0], w, lane);
            stage_tile<64>(Bb + kn, I, &bt[cur ^ 1][0][0], w, lane);
        }
#pragma unroll
        for (int ks = 0; ks < 64; ks += 32) {
            short8 af[4], bf[2];
#pragma unroll
            for (int i = 0; i < 4; i++)
                af[i] = *(const short8*)swz_ptr(&at[cur][0][0], wm * 64 + i * 16 + l16, ks + quad * 8);
#pragma unroll
            for (int j = 0; j < 2; j++)
                bf[j] = *(const short8*)swz_ptr(&bt[cur][0][0], wn * 32 + j * 16 + l16, ks + quad * 8);
#pragma unroll
            for (int mt = 0; mt < 4; mt++)
#pragma unroll
                for (int nt = 0; nt < 2; nt++)
                    acc[mt][nt] = MFMA16(af[mt], bf[nt], acc[mt][nt]);
        }
        __syncthreads();
    }
}

// ---------------------------------------------------------------------------
// Fused q/k/v projections (verified, unchanged).  grid (24, 16, NB).
// ---------------------------------------------------------------------------
__global__ __launch_bounds__(256) void proj_qkv(
    const u16* __restrict__ wq, const u16* __restrict__ wk, const u16* __restrict__ wv,
    const u16* __restrict__ xc, const u16* __restrict__ cc,
    const float* __restrict__ qb, const float* __restrict__ kb, const float* __restrict__ vbi,
    const int* __restrict__ cntQ, const int* __restrict__ cntK,
    const float* __restrict__ gq, const float* __restrict__ bq,
    const float* __restrict__ gk, const float* __restrict__ bk,
    const float* __restrict__ gv, const float* __restrict__ bv,
    u16* __restrict__ qc, u16* __restrict__ kc, u16* __restrict__ vn) {
    int mat = blockIdx.x >> 3;
    int o0 = (blockIdx.x & 7) * 128;
    int l0 = blockIdx.y * 64;
    int b = blockIdx.z;
    int limit = (mat == 0) ? cntQ[b] : cntK[b];
    if (l0 >= limit) return;
    __shared__ u16 at[2][128][64];
    __shared__ u16 bt[2][64][64];
    __shared__ float sg[64], sbe[64], sbias[128];
    int tid = threadIdx.x;
    int w = tid >> 6, lane = tid & 63, quad = lane >> 4, l16 = lane & 15;
    int wm = w & 1, wn = w >> 1;
    const u16* A = mat == 0 ? wq : (mat == 1 ? wk : wv);
    const u16* BT = mat == 0 ? xc : cc;
    const float* bias = mat == 0 ? qb : (mat == 1 ? kb : vbi);
    int I = mat == 0 ? EE : CCH;
    if (tid < 64) {
        const float* gsrc = mat == 0 ? gq : (mat == 1 ? gk : gv);
        const float* bsrc = mat == 0 ? bq : (mat == 1 ? bk : bv);
        sg[tid] = gsrc[tid];
        sbe[tid] = bsrc[tid];
    }
    if (tid < 128) sbias[tid] = bias[o0 + tid];

    f32x4 acc[4][2] = {};
    gemm_core(A, BT + (size_t)b * 1024 * I, I, o0, l0, at, bt, acc);

    float scale = mat == 0 ? QSCALE : 1.0f;
    int h = (o0 >> 6) + wm;
    int bh = b * NH + h;
#pragma unroll
    for (int nt = 0; nt < 2; nt++) {
        int l = l0 + wn * 32 + nt * 16 + l16;
        float vbuf[16];
        float s = 0.f;
#pragma unroll
        for (int mt = 0; mt < 4; mt++)
#pragma unroll
            for (int reg = 0; reg < 4; reg++) {
                float v = acc[mt][nt][reg] + sbias[wm * 64 + mt * 16 + quad * 4 + reg];
                vbuf[mt * 4 + reg] = v; s += v;
            }
        s += __shfl_xor(s, 16); s += __shfl_xor(s, 32);
        float mean = s * (1.f / 64);
        float s2 = 0.f;
#pragma unroll
        for (int i = 0; i < 16; i++) { float dv = vbuf[i] - mean; s2 += dv * dv; }
        s2 += __shfl_xor(s2, 16); s2 += __shfl_xor(s2, 32);
        float r = rsqrtf(s2 * (1.f / 64) + EPSF);
        if (l < limit) {
            if (mat < 2) {
                u16* outT = mat == 0 ? qc : kc;
                u16* op = outT + ((size_t)bh * 1024 + l) * 64;
#pragma unroll
                for (int mt = 0; mt < 4; mt++) {
                    u16x4 pk;
#pragma unroll
                    for (int reg = 0; reg < 4; reg++) {
                        int d = mt * 16 + quad * 4 + reg;
                        pk[reg] = f2bu(((vbuf[mt * 4 + reg] - mean) * r * sg[d] + sbe[d]) * scale);
                    }
                    *(u16x4*)&op[mt * 16 + quad * 4] = pk;
                }
            } else {
#pragma unroll
                for (int mt = 0; mt < 4; mt++)
#pragma unroll
                    for (int reg = 0; reg < 4; reg++) {
                        int d = mt * 16 + quad * 4 + reg;
                        vn[((size_t)b * EE + h * 64 + d) * 1024 + l] =
                            f2bu((vbuf[mt * 4 + reg] - mean) * r * sg[d] + sbe[d]);
                    }
            }
        }
    }
}

// ---------------------------------------------------------------------------
// attn_stats: BARRIER-FREE direct-MFMA. K-fragments live in registers for the
// whole t-sweep; q-fragments ping-pong (2-deep reg prefetch). No LDS in the
// hot loop (1 KB lp + one syncthreads only in the epilogue reduce).
// P[t][s] = exp2(q'.k) (zeroed s-tail); fold 1/l_s in-place into vn.
// grid (16, NH, NB).
// ---------------------------------------------------------------------------
__global__ __launch_bounds__(256) void attn_stats(
    const u16* __restrict__ qc, const u16* __restrict__ kc,
    const int* __restrict__ cntQ, const int* __restrict__ cntK,
    u16* __restrict__ vn, u16* __restrict__ P) {
    int s0 = blockIdx.x * 64, h = blockIdx.y, b = blockIdx.z;
    int Sc = cntK[b], Tc = cntQ[b];
    if (s0 >= Sc) return;
    __shared__ float lp[4][64];
    int tid = threadIdx.x;
    int w = tid >> 6, lane = tid & 63, quad = lane >> 4, l16 = lane & 15;
    int head = b * NH + h;
    const u16* kp = kc + (size_t)head * SS * DHH;
    const u16* qp = qc + (size_t)head * TT * DHH;
    u16* Pb = P + (size_t)head * TT * SS;

    // K-fragments resident in registers (rows s0 + mt*16 + l16)
    short8 af[4][2];
#pragma unroll
    for (int mt = 0; mt < 4; mt++) {
        const u16* kr = kp + (size_t)(s0 + mt * 16 + l16) * DHH + quad * 8;
        af[mt][0] = *(const short8*)kr;
        af[mt][1] = *(const short8*)(kr + 32);
    }
    const u16* qr = qp + (size_t)(w * 16 + l16) * DHH + quad * 8;
    float rl[4][4] = {};

#define LOADQ(B, tb) { B[0] = *(const short8*)(qr + (size_t)(tb) * DHH); \
                       B[1] = *(const short8*)(qr + (size_t)(tb) * DHH + 32); }
#define SBODY(B, tb) { \
        f32x4 acc[4] = {}; \
        _Pragma("unroll") \
        for (int mt = 0; mt < 4; mt++) { \
            acc[mt] = MFMA16(af[mt][0], B[0], acc[mt]); \
            acc[mt] = MFMA16(af[mt][1], B[1], acc[mt]); \
        } \
        int tcol = (tb) + w * 16 + l16; \
        int tok = tcol < Tc; \
        _Pragma("unroll") \
        for (int mt = 0; mt < 4; mt++) { \
            u16x4 pk; \
            _Pragma("unroll") \
            for (int reg = 0; reg < 4; reg++) { \
                int sl = s0 + mt * 16 + quad * 4 + reg; \
                float e = EXP2(acc[mt][reg]); \
                if (tok) rl[mt][reg] += e; \
                pk[reg] = (sl < Sc) ? f2bu(e) : (u16)0; \
            } \
            *(u16x4*)&Pb[(size_t)tcol * SS + s0 + mt * 16 + quad * 4] = pk; \
        } }

    short8 B0[2], B1[2];
    LOADQ(B0, 0);
    for (int t0 = 0; t0 < Tc; t0 += 128) {
        if (t0 + 64 < Tc) LOADQ(B1, t0 + 64);
        SBODY(B0, t0);
        if (t0 + 64 < Tc) {
            if (t0 + 128 < Tc) LOADQ(B0, t0 + 128);
            SBODY(B1, t0 + 64);
        }
    }
#undef LOADQ
#undef SBODY

#pragma unroll
    for (int mt = 0; mt < 4; mt++) {
#pragma unroll
        for (int reg = 0; reg < 4; reg++) {
            float v = rl[mt][reg];
            v += __shfl_xor(v, 1); v += __shfl_xor(v, 2);
            v += __shfl_xor(v, 4); v += __shfl_xor(v, 8);
            if (l16 == 0) lp[w][mt * 16 + quad * 4 + reg] = v;
        }
    }
    __syncthreads();
    {   // fold 1/l_s into vn in-place (coalesced along s)
        int so = tid & 63, dg = tid >> 6;
        int s = s0 + so;
        float lv = lp[0][so] + lp[1][so] + lp[2][so] + lp[3][so];
        float wsc = (lv > 0.f) ? (1.f / lv) : 0.f;
        u16* vrow = vn + ((size_t)b * EE + h * 64) * SS;
        int live = s < Sc;
#pragma unroll
        for (int i = 0; i < 16; i++) {
            int d = dg * 16 + i;
            size_t ad = (size_t)d * SS + s;
            vrow[ad] = live ? f2bu(bu2f(vrow[ad]) * wsc) : (u16)0;
        }
    }
}

// ---------------------------------------------------------------------------
// attn_pv: BARRIER-FREE, LDS-FREE pure GEMM.  Operands swapped vs old code
// (A = P rows t, B = vn' rows d) so D[t][d] stores straight into ac layout --
// no transpose staging.  2-deep register ping-pong prefetch.  grid (16,NH,NB).
// ---------------------------------------------------------------------------
__global__ __launch_bounds__(256) void attn_pv(
    const u16* __restrict__ vn, const u16* __restrict__ P,
    const int* __restrict__ cntQ, const int* __restrict__ cntK,
    u16* __restrict__ ac) {
    int t0 = blockIdx.x * 64, h = blockIdx.y, b = blockIdx.z;
    int Tc = cntQ[b], Sc = cntK[b];
    if (t0 >= Tc) return;
    int Kc = (Sc + 63) & ~63;
    int tid = threadIdx.x;
    int w = tid >> 6, lane = tid & 63, quad = lane >> 4, l16 = lane & 15;
    int head = b * NH + h;
    const u16* Pb = P + (size_t)head * TT * SS;
    const u16* a0 = Pb + (size_t)(t0 +  0 + l16) * SS + quad * 8;
    const u16* a1 = Pb + (size_t)(t0 + 16 + l16) * SS + quad * 8;
    const u16* a2 = Pb + (size_t)(t0 + 32 + l16) * SS + quad * 8;
    const u16* a3 = Pb + (size_t)(t0 + 48 + l16) * SS + quad * 8;
    const u16* br = vn + ((size_t)b * EE + h * 64 + w * 16 + l16) * SS + quad * 8;

#define LOADF(A, B, k0) { \
        A[0][0] = *(const short8*)(a0 + (k0));      A[0][1] = *(const short8*)(a0 + (k0) + 32); \
        A[1][0] = *(const short8*)(a1 + (k0));      A[1][1] = *(const short8*)(a1 + (k0) + 32); \
        A[2][0] = *(const short8*)(a2 + (k0));      A[2][1] = *(const short8*)(a2 + (k0) + 32); \
        A[3][0] = *(const short8*)(a3 + (k0));      A[3][1] = *(const short8*)(a3 + (k0) + 32); \
        B[0]    = *(const short8*)(br + (k0));      B[1]    = *(const short8*)(br + (k0) + 32); }
#define MF8(A, B) { \
        _Pragma("unroll") \
        for (int mt = 0; mt < 4; mt++) { \
            acc[mt] = MFMA16(A[mt][0], B[0], acc[mt]); \
            acc[mt] = MFMA16(A[mt][1], B[1], acc[mt]); \
        } }

    short8 A0[4][2], B0[2], A1[4][2], B1[2];
    f32x4 acc[4] = {};
    LOADF(A0, B0, 0);
    for (int k0 = 0; k0 < Kc; k0 += 128) {
        if (k0 + 64 < Kc) LOADF(A1, B1, k0 + 64);
        MF8(A0, B0);
        if (k0 + 64 < Kc) {
            if (k0 + 128 < Kc) LOADF(A0, B0, k0 + 128);
            MF8(A1, B1);
        }
    }
#undef LOADF
#undef MF8

    // D[t][d]: t = t0 + mt*16 + quad*4 + reg, d = w*16 + l16  -> direct ac store
    int d = w * 16 + l16;
#pragma unroll
    for (int mt = 0; mt < 4; mt++)
#pragma unroll
        for (int reg = 0; reg < 4; reg++) {
            int t = t0 + mt * 16 + quad * 4 + reg;
            if (t < Tc)
                ac[((size_t)b * TT + t) * EE + h * 64 + d] = f2bu(acc[mt][reg]);
        }
}

// ---------------------------------------------------------------------------
// proj_o: BARRIER-FREE, LDS-FREE direct-MFMA 64x64 tiles.  A = won rows o,
// B = ac rows l.  K = EE = 1024, 2-deep register ping-pong.  Epilogue adds
// bias + f32 residual and scatters through tIdx.  grid (16, 16, NB).
// ---------------------------------------------------------------------------
__global__ __launch_bounds__(256) void proj_o(
    const u16* __restrict__ won, const u16* __restrict__ ac,
    const float* __restrict__ obi, const int* __restrict__ tIdx,
    const int* __restrict__ cntQ, const float* __restrict__ x,
    float* __restrict__ out) {
    int o0 = blockIdx.x * 64, l0 = blockIdx.y * 64, b = blockIdx.z;
    int Tc = cntQ[b];
    if (l0 >= Tc) return;
    int tid = threadIdx.x;
    int w = tid >> 6, lane = tid & 63, quad = lane >> 4, l16 = lane & 15;
    const u16* a0 = won + (size_t)(o0 +  0 + l16) * EE + quad * 8;
    const u16* a1 = won + (size_t)(o0 + 16 + l16) * EE + quad * 8;
    const u16* a2 = won + (size_t)(o0 + 32 + l16) * EE + quad * 8;
    const u16* a3 = won + (size_t)(o0 + 48 + l16) * EE + quad * 8;
    const u16* br = ac + ((size_t)b * TT + l0 + w * 16 + l16) * EE + quad * 8;

#define LOADF(A, B, k0) { \
        A[0][0] = *(const short8*)(a0 + (k0));      A[0][1] = *(const short8*)(a0 + (k0) + 32); \
        A[1][0] = *(const short8*)(a1 + (k0));      A[1][1] = *(const short8*)(a1 + (k0) + 32); \
        A[2][0] = *(const short8*)(a2 + (k0));      A[2][1] = *(const short8*)(a2 + (k0) + 32); \
        A[3][0] = *(const short8*)(a3 + (k0));      A[3][1] = *(const short8*)(a3 + (k0) + 32); \
        B[0]    = *(const short8*)(br + (k0));      B[1]    = *(const short8*)(br + (k0) + 32); }
#define MF8(A, B) { \
        _Pragma("unroll") \
        for (int mt = 0; mt < 4; mt++) { \
            acc[mt] = MFMA16(A[mt][0], B[0], acc[mt]); \
            acc[mt] = MFMA16(A[mt][1], B[1], acc[mt]); \
        } }

    short8 A0[4][2], B0[2], A1[4][2], B1[2];
    f32x4 acc[4] = {};
    LOADF(A0, B0, 0);
    for (int k0 = 0; k0 < EE; k0 += 128) {
        LOADF(A1, B1, k0 + 64);
        MF8(A0, B0);
        if (k0 + 128 < EE) LOADF(A0, B0, k0 + 128);
        MF8(A1, B1);
    }
#undef LOADF
#undef MF8

    // D[o][l]: o = o0 + mt*16 + quad*4 + reg, l = l0 + w*16 + l16
    int l = l0 + w * 16 + l16;
    if (l < Tc) {
        int treal = tIdx[(size_t)b * 1024 + l];
#pragma unroll
        for (int mt = 0; mt < 4; mt++)
#pragma unroll
            for (int reg = 0; reg < 4; reg++) {
                int o = o0 + mt * 16 + quad * 4 + reg;
                size_t off = ((size_t)b * EE + o) * TT + treal;
                out[off] = acc[mt][reg] + obi[o] + x[off];
            }
    }
}

// ---------------------------------------------------------------------------
extern "C" void kernel_launch(void* const* d_in, const int* in_sizes, int n_in,
                              void* d_out, int out_size, void* d_ws, size_t ws_size,
                              hipStream_t stream) {
    const float* x        = (const float*)d_in[0];
    const float* ctx      = (const float*)d_in[1];
    const int*   mask     = (const int*)d_in[2];
    const int*   mask_ctx = (const int*)d_in[3];
    const float* qw  = (const float*)d_in[4];
    const float* qbi = (const float*)d_in[5];
    const float* kw  = (const float*)d_in[6];
    const float* kbi = (const float*)d_in[7];
    const float* vw  = (const float*)d_in[8];
    const float* vbi = (const float*)d_in[9];
    const float* ow  = (const float*)d_in[10];
    const float* obi = (const float*)d_in[11];
    const float* gq = (const float*)d_in[12];
    const float* bq = (const float*)d_in[13];
    const float* gk = (const float*)d_in[14];
    const float* bk = (const float*)d_in[15];
    const float* gv = (const float*)d_in[16];
    const float* bv = (const float*)d_in[17];

    // workspace carve (~190 MB)
    u16* p = (u16*)d_ws;
    u16* wqn = p; p += (size_t)EE * EE;
    u16* wkn = p; p += (size_t)EE * CCH;
    u16* wvn = p; p += (size_t)EE * CCH;
    u16* won = p; p += (size_t)EE * EE;
    u16* xc  = p; p += (size_t)NB * TT * EE;        // compact [b][pos][e]
    u16* cc  = p; p += (size_t)NB * SS * CCH;       // compact [b][pos][c]
    u16* vn  = p; p += (size_t)NB * EE * SS;        // LN'd V; 1/l folded in-place
    u16* qc  = p; p += (size_t)NB * NH * TT * DHH;  // compact q [bh][pos][d]
    u16* kc  = p; p += (size_t)NB * NH * SS * DHH;  // compact k [bh][pos][d]
    u16* ac  = p; p += (size_t)NB * TT * EE;        // attn out compact [b][pos][e]
    u16* P   = p; p += (size_t)NB * NH * TT * SS;   // exp2 scores [bh][t][s]
    int* tIdx = (int*)p;
    int* sIdx = tIdx + NB * 1024;
    int* cntQ = sIdx + NB * 1024;
    int* cntK = cntQ + NB;

    // 1) prep
    prep<<<PREP_FILL_END, 256, 0, stream>>>(
        qw, kw, vw, ow, wqn, wkn, wvn, won, x, ctx, mask, mask_ctx,
        xc, cc, tIdx, sIdx, cntQ, cntK, (float*)d_out);

    // 2) q/k/v projections + LN epilogue
    proj_qkv<<<dim3(24, 16, NB), 256, 0, stream>>>(
        wqn, wkn, wvn, xc, cc, qbi, kbi, vbi, cntQ, cntK,
        gq, bq, gk, bk, gv, bv, qc, kc, vn);

    // 3) QK^T once -> P, fold 1/l_s into vn (barrier-free direct MFMA)
    attn_stats<<<dim3(16, NH, NB), 256, 0, stream>>>(
        qc, kc, cntQ, cntK, vn, P);

    // 4) PV pure GEMM, direct ac store (barrier-free, LDS-free)
    attn_pv<<<dim3(16, NH, NB), 256, 0, stream>>>(
        vn, P, cntQ, cntK, ac);

    // 5) o-proj + bias + residual, scatter via tIdx (barrier-free, LDS-free)
    proj_o<<<dim3(16, 16, NB), 256, 0, stream>>>(
        won, ac, obi, tIdx, cntQ, x, (float*)d_out);
}

// Round 8
// 223.085 us; speedup vs baseline: 2.3256x; 1.3721x over previous
//
#include <hip/hip_runtime.h>

// Problem constants (B=4, T=S=1024, E=1024, CTX=768, H=16, DH=64)
#define NB 4
#define TT 1024
#define SS 1024
#define EE 1024
#define CCH 768
#define NH 16
#define DHH 64
#define EPSF 1e-5f
// SCALE = 1024 // (16**0.5) = 256.  Fold 1/256 * log2(e) into q so that
// exp(score/256) == exp2(q'.k) with a single v_exp_f32.
#define QSCALE (1.4426950408889634f / 256.0f)

typedef unsigned short u16;
typedef __attribute__((ext_vector_type(8))) short short8;       // MFMA A/B frag
typedef __attribute__((ext_vector_type(8))) unsigned short u16x8;
typedef __attribute__((ext_vector_type(4))) unsigned short u16x4;
typedef __attribute__((ext_vector_type(4))) float f32x4;        // MFMA C/D frag

__device__ __forceinline__ u16 f2bu(float f) {
    union { float f; unsigned u; } x; x.f = f;
    unsigned r = x.u + 0x7fffu + ((x.u >> 16) & 1u);
    return (u16)(r >> 16);
}
__device__ __forceinline__ float bu2f(u16 u) {
    union { unsigned u; float f; } x; x.u = ((unsigned)u) << 16; return x.f;
}

#if __has_builtin(__builtin_amdgcn_exp2f)
#define EXP2(x) __builtin_amdgcn_exp2f(x)
#else
#define EXP2(x) exp2f(x)
#endif

#define MFMA16(a, b, c) __builtin_amdgcn_mfma_f32_16x16x32_bf16((a), (b), (c), 0, 0, 0)

// prep block-range offsets
#define PREP_WS_END   4096                  // 4 mats x 1024 rows
#define PREP_SCAN_END (PREP_WS_END + 8)     // 2 masks x 4 batches
#define PREP_TR_END   (PREP_SCAN_END + 1792) // 16 x 28 x 4 transpose tiles
#define PREP_FILL_END (PREP_TR_END + 4096)  // 4 batches x 1024 rows fill

// ---------------------------------------------------------------------------
// PREP mega-kernel (all mutually independent prologue work, 1D grid):
//   [0,4096)      weight standardization -> bf16
//   [4096,4104)   mask prefix scan -> tIdx/sIdx + counts
//   [4104,5896)   compacting transpose x/ctx -> bf16 [b][pos][R]
//   [5896,9992)   masked-column residual fill: out[b,o,t] = x[b,o,t] (!mask[t])
// ---------------------------------------------------------------------------
__global__ __launch_bounds__(256) void prep(
    const float* __restrict__ qw, const float* __restrict__ kw,
    const float* __restrict__ vw, const float* __restrict__ ow,
    u16* __restrict__ wqn, u16* __restrict__ wkn,
    u16* __restrict__ wvn, u16* __restrict__ won,
    const float* __restrict__ x, const float* __restrict__ ctx,
    const int* __restrict__ mask, const int* __restrict__ mask_ctx,
    u16* __restrict__ xc, u16* __restrict__ cc,
    int* __restrict__ tIdx, int* __restrict__ sIdx,
    int* __restrict__ cntQ, int* __restrict__ cntK,
    float* __restrict__ outF) {
    __shared__ float tile[64][65];
    __shared__ int spos[64], smask[64], wtoti[4];
    __shared__ float sa[4], sb2[4], smean, srstd;
    int bid = blockIdx.x, tid = threadIdx.x;

    if (bid < PREP_WS_END) {
        int mat = bid >> 10, row = bid & 1023;
        const float* w = mat == 0 ? qw : (mat == 1 ? kw : (mat == 2 ? vw : ow));
        u16* wn = mat == 0 ? wqn : (mat == 1 ? wkn : (mat == 2 ? wvn : won));
        int I = (mat == 1 || mat == 2) ? CCH : EE;
        const float* wr = w + (size_t)row * I;
        float s = 0.f, s2 = 0.f;
        for (int i = tid; i < I; i += 256) { float v = wr[i]; s += v; s2 += v * v; }
#pragma unroll
        for (int off = 32; off > 0; off >>= 1) { s += __shfl_down(s, off); s2 += __shfl_down(s2, off); }
        int wid = tid >> 6;
        if ((tid & 63) == 0) { sa[wid] = s; sb2[wid] = s2; }
        __syncthreads();
        if (tid == 0) {
            float ts = sa[0] + sa[1] + sa[2] + sa[3];
            float ts2 = sb2[0] + sb2[1] + sb2[2] + sb2[3];
            float mean = ts / (float)I;
            float var = ts2 / (float)I - mean * mean;
            smean = mean; srstd = rsqrtf(var + EPSF);
        }
        __syncthreads();
        float mean = smean, r = srstd;
        u16* wo = wn + (size_t)row * I;
        for (int i = tid; i < I; i += 256) wo[i] = f2bu((wr[i] - mean) * r);
        return;
    }
    if (bid < PREP_SCAN_END) {
        int t = bid - PREP_WS_END;
        int which = t & 1, b = t >> 1;
        const int* m = (which ? mask_ctx : mask) + b * 1024;
        int* idx = (which ? sIdx : tIdx) + b * 1024;
        int* cnt = (which ? cntK : cntQ) + b;
        int base = tid * 4;
        int v[4]; int s = 0;
#pragma unroll
        for (int i = 0; i < 4; i++) { v[i] = m[base + i] ? 1 : 0; s += v[i]; }
        int lane = tid & 63, wid = tid >> 6;
        int inc = s;
#pragma unroll
        for (int off = 1; off < 64; off <<= 1) {
            int o = __shfl_up(inc, off);
            if (lane >= off) inc += o;
        }
        if (lane == 63) wtoti[wid] = inc;
        __syncthreads();
        int woff = 0;
        for (int i = 0; i < wid; i++) woff += wtoti[i];
        int p = woff + inc - s;
#pragma unroll
        for (int i = 0; i < 4; i++) {
            if (v[i]) idx[p] = base + i;
            p += v[i];
        }
        if (tid == 255) *cnt = p;
        return;
    }
    if (bid < PREP_TR_END) {
        int t = bid - PREP_SCAN_END;
        int xb = t & 15; int rem = t >> 4;
        int yy = rem % 28, b = rem / 28;
        int mat = yy < 16 ? 0 : 1;
        int r0 = (mat == 0 ? yy : yy - 16) * 64;
        int R = mat == 0 ? EE : CCH;
        const float* in = mat == 0 ? x : ctx;
        const int* m = (mat == 0 ? mask : mask_ctx) + (size_t)b * 1024;
        u16* out = mat == 0 ? xc : cc;
        int c0 = xb * 64;
        const float* ip = in + (size_t)b * R * 1024;
        u16* op = out + (size_t)b * R * 1024;
#pragma unroll
        for (int mm = 0; mm < 16; mm++) {
            int id = tid + 256 * mm; int r = id >> 6, c = id & 63;
            tile[r][c] = ip[(size_t)(r0 + r) * 1024 + c0 + c];
        }
        int base = tid * 4;
        int v[4]; int s = 0;
#pragma unroll
        for (int i = 0; i < 4; i++) { v[i] = m[base + i] ? 1 : 0; s += v[i]; }
        int lane = tid & 63, wid = tid >> 6;
        int inc = s;
#pragma unroll
        for (int off = 1; off < 64; off <<= 1) {
            int o = __shfl_up(inc, off);
            if (lane >= off) inc += o;
        }
        if (lane == 63) wtoti[wid] = inc;
        __syncthreads();
        int woff = 0;
        for (int i = 0; i < wid; i++) woff += wtoti[i];
        int p = woff + inc - s;
#pragma unroll
        for (int i = 0; i < 4; i++) {
            int g = base + i;
            if (g >= c0 && g < c0 + 64) { spos[g - c0] = p; smask[g - c0] = v[i]; }
            p += v[i];
        }
        __syncthreads();
#pragma unroll
        for (int mm = 0; mm < 16; mm++) {
            int id = tid + 256 * mm; int rr = id >> 6, cc2 = id & 63;
            if (smask[rr])
                op[(size_t)spos[rr] * R + r0 + cc2] = f2bu(tile[cc2][rr]);
        }
        return;
    }
    {   // masked residual fill
        int f = bid - PREP_TR_END;
        int b = f >> 10, o = f & 1023;
        const float* xr = x + ((size_t)b * EE + o) * TT;
        float* orow = outF + ((size_t)b * EE + o) * TT;
        const int* mrow = mask + (size_t)b * TT;
        int4 mv = ((const int4*)mrow)[tid];
        float4 xv = ((const float4*)xr)[tid];
        int t4 = tid * 4;
        if (!mv.x) orow[t4 + 0] = xv.x;
        if (!mv.y) orow[t4 + 1] = xv.y;
        if (!mv.z) orow[t4 + 2] = xv.z;
        if (!mv.w) orow[t4 + 3] = xv.w;
    }
}

// ---------------------------------------------------------------------------
// GEMM core: 128x64 tile, 4 waves, each a 64x32 quadrant (4x2 16x16x32 frags).
// Prefetch distance 2 (I % 128 == 0 holds for 1024 and 768).
// ---------------------------------------------------------------------------
__device__ __forceinline__ void gemm_core(
    const u16* __restrict__ A, const u16* __restrict__ Bp, int I,
    int o0, int l0, u16 (*at)[72], u16 (*bt)[72], f32x4 (&acc)[4][2]) {
    int tid = threadIdx.x;
    int w = tid >> 6, lane = tid & 63, quad = lane >> 4, l16 = lane & 15;
    int wm = w & 1, wn = w >> 1;
    int rA = tid >> 3, cA = (tid & 7) * 8;
    u16x8 ra[2][4], rb[2][2];
#pragma unroll
    for (int p = 0; p < 2; p++) {
        int kb = p * 64;
#pragma unroll
        for (int m = 0; m < 4; m++)
            ra[p][m] = *(const u16x8*)&A[(size_t)(o0 + rA + 32 * m) * I + kb + cA];
#pragma unroll
        for (int m = 0; m < 2; m++)
            rb[p][m] = *(const u16x8*)&Bp[(size_t)(l0 + rA + 32 * m) * I + kb + cA];
    }
    for (int k0 = 0; k0 < I; k0 += 128) {
#pragma unroll
        for (int half = 0; half < 2; half++) {
            __syncthreads();
#pragma unroll
            for (int m = 0; m < 4; m++) *(u16x8*)&at[rA + 32 * m][cA] = ra[half][m];
#pragma unroll
            for (int m = 0; m < 2; m++) *(u16x8*)&bt[rA + 32 * m][cA] = rb[half][m];
            __syncthreads();
            int kpre = k0 + half * 64 + 128;
            if (kpre < I) {
#pragma unroll
                for (int m = 0; m < 4; m++)
                    ra[half][m] = *(const u16x8*)&A[(size_t)(o0 + rA + 32 * m) * I + kpre + cA];
#pragma unroll
                for (int m = 0; m < 2; m++)
                    rb[half][m] = *(const u16x8*)&Bp[(size_t)(l0 + rA + 32 * m) * I + kpre + cA];
            }
#pragma unroll
            for (int ks = 0; ks < 64; ks += 32) {
                short8 af[4], bf[2];
#pragma unroll
                for (int i = 0; i < 4; i++)
                    af[i] = *(const short8*)&at[wm * 64 + i * 16 + l16][ks + quad * 8];
#pragma unroll
                for (int j = 0; j < 2; j++)
                    bf[j] = *(const short8*)&bt[wn * 32 + j * 16 + l16][ks + quad * 8];
#pragma unroll
                for (int mt = 0; mt < 4; mt++)
#pragma unroll
                    for (int nt = 0; nt < 2; nt++)
                        acc[mt][nt] = MFMA16(af[mt], bf[nt], acc[mt][nt]);
            }
        }
    }
}

// 64x64-tile core (used by compact proj_o; 4x1 frags per wave).
__device__ __forceinline__ void gemm_core64(
    const u16* __restrict__ A, const u16* __restrict__ Bp, int I,
    int o0, int l0, u16 (*at)[72], u16 (*bt)[72], f32x4 (&acc)[4]) {
    int tid = threadIdx.x;
    int w = tid >> 6, lane = tid & 63, quad = lane >> 4, l16 = lane & 15;
    int rA = tid >> 3, cA = (tid & 7) * 8;
    u16x8 ra[2][2], rb[2][2];
#pragma unroll
    for (int p = 0; p < 2; p++) {
        int kb = p * 64;
#pragma unroll
        for (int m = 0; m < 2; m++) {
            ra[p][m] = *(const u16x8*)&A[(size_t)(o0 + rA + 32 * m) * I + kb + cA];
            rb[p][m] = *(const u16x8*)&Bp[(size_t)(l0 + rA + 32 * m) * I + kb + cA];
        }
    }
    for (int k0 = 0; k0 < I; k0 += 128) {
#pragma unroll
        for (int half = 0; half < 2; half++) {
            __syncthreads();
#pragma unroll
            for (int m = 0; m < 2; m++) {
                *(u16x8*)&at[rA + 32 * m][cA] = ra[half][m];
                *(u16x8*)&bt[rA + 32 * m][cA] = rb[half][m];
            }
            __syncthreads();
            int kpre = k0 + half * 64 + 128;
            if (kpre < I) {
#pragma unroll
                for (int m = 0; m < 2; m++) {
                    ra[half][m] = *(const u16x8*)&A[(size_t)(o0 + rA + 32 * m) * I + kpre + cA];
                    rb[half][m] = *(const u16x8*)&Bp[(size_t)(l0 + rA + 32 * m) * I + kpre + cA];
                }
            }
#pragma unroll
            for (int ks = 0; ks < 64; ks += 32) {
                short8 bf = *(const short8*)&bt[w * 16 + l16][ks + quad * 8];
#pragma unroll
                for (int mt = 0; mt < 4; mt++) {
                    short8 af = *(const short8*)&at[mt * 16 + l16][ks + quad * 8];
                    acc[mt] = MFMA16(af, bf, acc[mt]);
                }
            }
        }
    }
}

// ---------------------------------------------------------------------------
// Fused q/k/v projections over COMPACT columns + per-head LN epilogue (q,k).
// 128x64 tiles. grid (24, 16, NB) with x = (mat, o-tile): since gx=24 and
// gy-stride 24 = 0 mod 8, linear_id % 8 = x % 8 -> all l-tiles of one weight
// tile land on one XCD (L2 reuse of the weight tile).
// ---------------------------------------------------------------------------
__global__ __launch_bounds__(256) void proj_qkv(
    const u16* __restrict__ wq, const u16* __restrict__ wk, const u16* __restrict__ wv,
    const u16* __restrict__ xc, const u16* __restrict__ cc,
    const float* __restrict__ qb, const float* __restrict__ kb, const float* __restrict__ vbi,
    const int* __restrict__ cntQ, const int* __restrict__ cntK,
    const float* __restrict__ gq, const float* __restrict__ bq,
    const float* __restrict__ gk, const float* __restrict__ bk,
    u16* __restrict__ qc, u16* __restrict__ kc, u16* __restrict__ yv) {
    int mat = blockIdx.x >> 3;
    int o0 = (blockIdx.x & 7) * 128;
    int l0 = blockIdx.y * 64;
    int b = blockIdx.z;
    int limit = (mat == 0) ? cntQ[b] : cntK[b];
    if (l0 >= limit) return;
    __shared__ u16 at[128][72];
    __shared__ u16 bt[64][72];
    __shared__ float sg[64], sbe[64], sbias[128];
    int tid = threadIdx.x;
    int w = tid >> 6, lane = tid & 63, quad = lane >> 4, l16 = lane & 15;
    int wm = w & 1, wn = w >> 1;
    const u16* A = mat == 0 ? wq : (mat == 1 ? wk : wv);
    const u16* BT = mat == 0 ? xc : cc;
    const float* bias = mat == 0 ? qb : (mat == 1 ? kb : vbi);
    int I = mat == 0 ? EE : CCH;
    if (mat < 2 && tid < 64) {
        sg[tid] = (mat == 0 ? gq : gk)[tid];
        sbe[tid] = (mat == 0 ? bq : bk)[tid];
    }
    if (tid < 128) sbias[tid] = bias[o0 + tid];

    f32x4 acc[4][2] = {};
    gemm_core(A, BT + (size_t)b * 1024 * I, I, o0, l0, at, bt, acc);

    if (mat < 2) {
        u16* outT = mat == 0 ? qc : kc;
        float scale = mat == 0 ? QSCALE : 1.0f;
        int h = (o0 >> 6) + wm;
        int bh = b * NH + h;
#pragma unroll
        for (int nt = 0; nt < 2; nt++) {
            int l = l0 + wn * 32 + nt * 16 + l16;
            float vbuf[16];
            float s = 0.f;
#pragma unroll
            for (int mt = 0; mt < 4; mt++)
#pragma unroll
                for (int reg = 0; reg < 4; reg++) {
                    float v = acc[mt][nt][reg] + sbias[wm * 64 + mt * 16 + quad * 4 + reg];
                    vbuf[mt * 4 + reg] = v; s += v;
                }
            s += __shfl_xor(s, 16); s += __shfl_xor(s, 32);
            float mean = s * (1.f / 64);
            float s2 = 0.f;
#pragma unroll
            for (int i = 0; i < 16; i++) { float dv = vbuf[i] - mean; s2 += dv * dv; }
            s2 += __shfl_xor(s2, 16); s2 += __shfl_xor(s2, 32);
            float r = rsqrtf(s2 * (1.f / 64) + EPSF);
            if (l < limit) {
                u16* op = outT + ((size_t)bh * 1024 + l) * 64;
#pragma unroll
                for (int mt = 0; mt < 4; mt++) {
                    u16x4 pk;
#pragma unroll
                    for (int reg = 0; reg < 4; reg++) {
                        int d = mt * 16 + quad * 4 + reg;
                        pk[reg] = f2bu(((vbuf[mt * 4 + reg] - mean) * r * sg[d] + sbe[d]) * scale);
                    }
                    *(u16x4*)&op[mt * 16 + quad * 4] = pk;
                }
            }
        }
    } else {
#pragma unroll
        for (int nt = 0; nt < 2; nt++) {
            int l = l0 + wn * 32 + nt * 16 + l16;
            if (l < limit) {
#pragma unroll
                for (int mt = 0; mt < 4; mt++)
#pragma unroll
                    for (int reg = 0; reg < 4; reg++) {
                        int o = o0 + wm * 64 + mt * 16 + quad * 4 + reg;
                        float v = acc[mt][nt][reg] + sbias[wm * 64 + mt * 16 + quad * 4 + reg];
                        yv[((size_t)b * EE + o) * 1024 + l] = f2bu(v);
                    }
            }
        }
    }
}

// ---------------------------------------------------------------------------
// Pass A over COMPACT indices: l_s = sum_{t<Tc} exp2(q'.k) for compact s rows;
// then fused V LayerNorm on the compact column + 1/l_s fold -> vc.
// grid (16, NH, NB); blocks with s0 >= Sc exit.
// ---------------------------------------------------------------------------
__global__ __launch_bounds__(256) void attn_stats_mfma(
    const u16* __restrict__ qc, const u16* __restrict__ kc,
    const int* __restrict__ cntQ, const int* __restrict__ cntK,
    const float* __restrict__ gv, const float* __restrict__ bv,
    const u16* __restrict__ yv, u16* __restrict__ vc) {
    int s0 = blockIdx.x * 64, h = blockIdx.y, b = blockIdx.z;
    int Sc = cntK[b], Tc = cntQ[b];
    if (s0 >= Sc) return;
    __shared__ u16 kt[64][72];   // [s][d]
    __shared__ u16 qt[64][72];   // [t][d]
    __shared__ float lp[4][64];
    int tid = threadIdx.x;
    int w = tid >> 6, lane = tid & 63, quad = lane >> 4, l16 = lane & 15;
    int head = b * NH + h;
    const u16* kp = kc + (size_t)head * SS * DHH;
    const u16* qp = qc + (size_t)head * TT * DHH;
    int rA = tid >> 3, cA = (tid & 7) * 8;
#pragma unroll
    for (int m = 0; m < 2; m++)
        *(u16x8*)&kt[rA + 32 * m][cA] = *(const u16x8*)&kp[(size_t)(s0 + rA + 32 * m) * DHH + cA];
    u16x8 rq[2][2];
#pragma unroll
    for (int p = 0; p < 2; p++)
#pragma unroll
        for (int m = 0; m < 2; m++)
            rq[p][m] = *(const u16x8*)&qp[(size_t)(p * 64 + rA + 32 * m) * DHH + cA];
    float rl[4][4] = {};
    for (int t0 = 0; t0 < Tc; t0 += 128) {
#pragma unroll
        for (int half = 0; half < 2; half++) {
            int tb = t0 + half * 64;
            __syncthreads();
#pragma unroll
            for (int m = 0; m < 2; m++) *(u16x8*)&qt[rA + 32 * m][cA] = rq[half][m];
            __syncthreads();
            int tpre = tb + 128;
            if (tpre < TT) {
#pragma unroll
                for (int m = 0; m < 2; m++)
                    rq[half][m] = *(const u16x8*)&qp[(size_t)(tpre + rA + 32 * m) * DHH + cA];
            }
            int tcol = tb + w * 16 + l16;
            f32x4 acc[4] = {};
#pragma unroll
            for (int ks = 0; ks < 64; ks += 32) {
                short8 bf = *(const short8*)&qt[w * 16 + l16][ks + quad * 8];
#pragma unroll
                for (int mt = 0; mt < 4; mt++) {
                    short8 af = *(const short8*)&kt[mt * 16 + l16][ks + quad * 8];
                    acc[mt] = MFMA16(af, bf, acc[mt]);
                }
            }
            if (tcol < Tc) {
#pragma unroll
                for (int mt = 0; mt < 4; mt++)
#pragma unroll
                    for (int reg = 0; reg < 4; reg++)
                        rl[mt][reg] += EXP2(acc[mt][reg]);
            }
        }
    }
#pragma unroll
    for (int mt = 0; mt < 4; mt++) {
#pragma unroll
        for (int reg = 0; reg < 4; reg++) {
            float v = rl[mt][reg];
            v += __shfl_xor(v, 1); v += __shfl_xor(v, 2);
            v += __shfl_xor(v, 4); v += __shfl_xor(v, 8);
            if (l16 == 0) lp[w][mt * 16 + quad * 4 + reg] = v;
        }
    }
    __syncthreads();
    if (tid < 64 && s0 + tid < Sc) {
        int spos = s0 + tid;
        float lv = lp[0][tid] + lp[1][tid] + lp[2][tid] + lp[3][tid];
        float wsc = lv > 0.f ? (1.f / lv) : 0.f;
        const u16* vin = yv + ((size_t)b * EE + h * 64) * SS + spos;
        u16* vout = vc + ((size_t)b * EE + h * 64) * SS + spos;
        float sm = 0.f, s2 = 0.f;
        float vals[DHH];
#pragma unroll
        for (int d = 0; d < DHH; d++) {
            float v = bu2f(vin[(size_t)d * SS]);
            vals[d] = v; sm += v; s2 += v * v;
        }
        float mean = sm * (1.f / DHH);
        float var = s2 * (1.f / DHH) - mean * mean;
        float r = rsqrtf(var + EPSF);
#pragma unroll
        for (int d = 0; d < DHH; d++)
            vout[(size_t)d * SS] = f2bu(((vals[d] - mean) * r * gv[d] + bv[d]) * wsc);
    }
}

// ---------------------------------------------------------------------------
// Pass B over COMPACT indices: out[d][t] = sum_{s<Sc} V'[d][s]*exp2(q'.k).
// Output written DENSE into compact ac [b][pos][e] (no scatter).
// grid (16, NH, NB).
// ---------------------------------------------------------------------------
__global__ __launch_bounds__(256) void attn_pv_mfma(
    const u16* __restrict__ qc, const u16* __restrict__ kc, const u16* __restrict__ vc,
    const int* __restrict__ cntQ, const int* __restrict__ cntK,
    u16* __restrict__ ac) {
    int t0 = blockIdx.x * 64, h = blockIdx.y, b = blockIdx.z;
    int Tc = cntQ[b], Sc = cntK[b];
    if (t0 >= Tc) return;
    __shared__ u16 qt[64][72];   // [t][d]
    __shared__ u16 kt[64][72];   // [s][d]
    __shared__ u16 vt[64][72];   // [d][s]
    __shared__ u16 pt[64][72];   // [t][s] wave-local; reused for out tile
    int tid = threadIdx.x;
    int w = tid >> 6, lane = tid & 63, quad = lane >> 4, l16 = lane & 15;
    int head = b * NH + h;
    const u16* qp = qc + (size_t)head * TT * DHH;
    const u16* kp = kc + (size_t)head * SS * DHH;
    const u16* vp = vc + ((size_t)head * DHH) * SS;
    int rA = tid >> 3, cA = (tid & 7) * 8;
#pragma unroll
    for (int m = 0; m < 2; m++)
        *(u16x8*)&qt[rA + 32 * m][cA] = *(const u16x8*)&qp[(size_t)(t0 + rA + 32 * m) * DHH + cA];
    u16x8 rk[2][2], rv[2][2];
#pragma unroll
    for (int p = 0; p < 2; p++)
#pragma unroll
        for (int m = 0; m < 2; m++) {
            rk[p][m] = *(const u16x8*)&kp[(size_t)(p * 64 + rA + 32 * m) * DHH + cA];
            rv[p][m] = *(const u16x8*)&vp[(size_t)(rA + 32 * m) * SS + p * 64 + cA];
        }
    int tl = w * 16 + l16;

    f32x4 oacc[4] = {};
    for (int s0 = 0; s0 < Sc; s0 += 128) {
#pragma unroll
        for (int half = 0; half < 2; half++) {
            int sb = s0 + half * 64;
            if (sb >= Sc) break;
            __syncthreads();
#pragma unroll
            for (int m = 0; m < 2; m++) {
                *(u16x8*)&kt[rA + 32 * m][cA] = rk[half][m];
                *(u16x8*)&vt[rA + 32 * m][cA] = rv[half][m];
            }
            __syncthreads();
            int spre = sb + 128;
            if (spre < SS) {
#pragma unroll
                for (int m = 0; m < 2; m++) {
                    rk[half][m] = *(const u16x8*)&kp[(size_t)(spre + rA + 32 * m) * DHH + cA];
                    rv[half][m] = *(const u16x8*)&vp[(size_t)(rA + 32 * m) * SS + spre + cA];
                }
            }
            f32x4 acc[4] = {};
#pragma unroll
            for (int ks = 0; ks < 64; ks += 32) {
                short8 bf = *(const short8*)&qt[tl][ks + quad * 8];
#pragma unroll
                for (int mt = 0; mt < 4; mt++) {
                    short8 af = *(const short8*)&kt[mt * 16 + l16][ks + quad * 8];
                    acc[mt] = MFMA16(af, bf, acc[mt]);
                }
            }
#pragma unroll
            for (int mt = 0; mt < 4; mt++) {
                u16x4 pk;
#pragma unroll
                for (int reg = 0; reg < 4; reg++) {
                    int sl = mt * 16 + quad * 4 + reg;
                    pk[reg] = (sb + sl < Sc) ? f2bu(EXP2(acc[mt][reg])) : (u16)0;
                }
                *(u16x4*)&pt[tl][mt * 16 + quad * 4] = pk;
            }
#pragma unroll
            for (int ks = 0; ks < 64; ks += 32) {
                short8 bf = *(const short8*)&pt[tl][ks + quad * 8];
#pragma unroll
                for (int mt = 0; mt < 4; mt++) {
                    short8 af = *(const short8*)&vt[mt * 16 + l16][ks + quad * 8];
                    oacc[mt] = MFMA16(af, bf, oacc[mt]);
                }
            }
        }
    }
    __syncthreads();
#pragma unroll
    for (int mt = 0; mt < 4; mt++) {
        u16x4 pk;
#pragma unroll
        for (int reg = 0; reg < 4; reg++) pk[reg] = f2bu(oacc[mt][reg]);
        *(u16x4*)&pt[tl][mt * 16 + quad * 4] = pk;
    }
    __syncthreads();
#pragma unroll
    for (int i = 0; i < 2; i++) {
        int id = tid * 2 + i;
        int r = id >> 3, c = (id & 7) * 8;
        if (t0 + r < Tc)
            *(u16x8*)&ac[((size_t)b * TT + t0 + r) * EE + h * 64 + c] =
                *(const u16x8*)&pt[r][c];
    }
}

// ---------------------------------------------------------------------------
// Output projection over COMPACT columns (+bias +f32 residual) -> f32,
// scattered through tIdx. Masked columns were pre-filled by prep.
// 64x64 tiles; grid (16, 16, NB): x = o-tile (16 % 8 == 0 -> XCD-stable),
// y = compact l-tile (exit past Tc).
// ---------------------------------------------------------------------------
__global__ __launch_bounds__(256) void proj_o(
    const u16* __restrict__ won, const u16* __restrict__ ac,
    const float* __restrict__ obi, const int* __restrict__ tIdx,
    const int* __restrict__ cntQ, const float* __restrict__ x,
    float* __restrict__ out) {
    int o0 = blockIdx.x * 64, l0 = blockIdx.y * 64, b = blockIdx.z;
    int Tc = cntQ[b];
    if (l0 >= Tc) return;
    __shared__ u16 at[64][72];
    __shared__ u16 bt[64][72];
    __shared__ float sbias[64];
    __shared__ int stre[64];
    int tid = threadIdx.x;
    int w = tid >> 6, lane = tid & 63, quad = lane >> 4, l16 = lane & 15;
    if (tid < 64) {
        sbias[tid] = obi[o0 + tid];
        stre[tid] = tIdx[(size_t)b * 1024 + l0 + tid];
    }
    f32x4 acc[4] = {};
    gemm_core64(won, ac + (size_t)b * TT * EE, EE, o0, l0, at, bt, acc);
    int l = l0 + w * 16 + l16;
    if (l < Tc) {
        int treal = stre[w * 16 + l16];
#pragma unroll
        for (int mt = 0; mt < 4; mt++)
#pragma unroll
            for (int reg = 0; reg < 4; reg++) {
                int o = o0 + mt * 16 + quad * 4 + reg;
                size_t off = ((size_t)b * EE + o) * TT + treal;
                out[off] = acc[mt][reg] + sbias[mt * 16 + quad * 4 + reg] + x[off];
            }
    }
}

// ---------------------------------------------------------------------------
extern "C" void kernel_launch(void* const* d_in, const int* in_sizes, int n_in,
                              void* d_out, int out_size, void* d_ws, size_t ws_size,
                              hipStream_t stream) {
    const float* x        = (const float*)d_in[0];
    const float* ctx      = (const float*)d_in[1];
    const int*   mask     = (const int*)d_in[2];
    const int*   mask_ctx = (const int*)d_in[3];
    const float* qw  = (const float*)d_in[4];
    const float* qbi = (const float*)d_in[5];
    const float* kw  = (const float*)d_in[6];
    const float* kbi = (const float*)d_in[7];
    const float* vw  = (const float*)d_in[8];
    const float* vbi = (const float*)d_in[9];
    const float* ow  = (const float*)d_in[10];
    const float* obi = (const float*)d_in[11];
    const float* gq = (const float*)d_in[12];
    const float* bq = (const float*)d_in[13];
    const float* gk = (const float*)d_in[14];
    const float* bk = (const float*)d_in[15];
    const float* gv = (const float*)d_in[16];
    const float* bv = (const float*)d_in[17];

    // workspace carve (~63 MB)
    u16* p = (u16*)d_ws;
    u16* wqn = p; p += (size_t)EE * EE;
    u16* wkn = p; p += (size_t)EE * CCH;
    u16* wvn = p; p += (size_t)EE * CCH;
    u16* won = p; p += (size_t)EE * EE;
    u16* xc  = p; p += (size_t)NB * TT * EE;        // compact [b][pos][e]
    u16* cc  = p; p += (size_t)NB * SS * CCH;       // compact [b][pos][c]
    u16* yv  = p; p += (size_t)NB * EE * SS;        // v proj out, compact columns
    u16* qc  = p; p += (size_t)NB * NH * TT * DHH;  // compact q [bh][pos][d]
    u16* kc  = p; p += (size_t)NB * NH * SS * DHH;  // compact k [bh][pos][d]
    u16* vc  = p; p += (size_t)NB * EE * SS;        // compact V' [b][E][pos]
    u16* ac  = p; p += (size_t)NB * TT * EE;        // attn out compact [b][pos][e]
    int* tIdx = (int*)p;
    int* sIdx = tIdx + NB * 1024;
    int* cntQ = sIdx + NB * 1024;
    int* cntK = cntQ + NB;

    // 1) prep: WS-norm + mask scan + compacting transpose + masked resid fill
    prep<<<PREP_FILL_END, 256, 0, stream>>>(
        qw, kw, vw, ow, wqn, wkn, wvn, won, x, ctx, mask, mask_ctx,
        xc, cc, tIdx, sIdx, cntQ, cntK, (float*)d_out);

    // 2) fused q/k/v projections over compact columns + LN epilogue (128x64)
    proj_qkv<<<dim3(24, 16, NB), 256, 0, stream>>>(
        wqn, wkn, wvn, xc, cc, qbi, kbi, vbi, cntQ, cntK,
        gq, bq, gk, bk, qc, kc, yv);

    // 3) softmax denominators on compact indices + fused V LN -> compact vc
    attn_stats_mfma<<<dim3(16, NH, NB), 256, 0, stream>>>(
        qc, kc, cntQ, cntK, gv, bv, yv, vc);

    // 4) PV on compact indices -> dense compact ac
    attn_pv_mfma<<<dim3(16, NH, NB), 256, 0, stream>>>(
        qc, kc, vc, cntQ, cntK, ac);

    // 5) o-proj over compact columns (+bias +resid), scatter via tIdx
    proj_o<<<dim3(16, 16, NB), 256, 0, stream>>>(
        won, ac, obi, tIdx, cntQ, x, (float*)d_out);
}